// Round 1
// baseline (456.198 us; speedup 1.0000x reference)
//
#include <hip/hip_runtime.h>
#include <stdint.h>

// Problem constants
#define HWN 196      // H*W tokens
#define CIN 2048     // input channels
#define DD  256      // slot dim
#define BB  64       // batch
#define SS  8        // slots
#define NPAD 208     // padded token rows for k/v buffers

typedef __attribute__((ext_vector_type(8))) short short8;
typedef __attribute__((ext_vector_type(4))) float f32x4;
typedef __attribute__((ext_vector_type(4))) unsigned short us4;

__device__ __forceinline__ ushort f2bf(float f) {
    union { float f; uint32_t u; } v; v.f = f;
    uint32_t u = v.u;
    return (ushort)((u + 0x7FFFu + ((u >> 16) & 1u)) >> 16);
}
__device__ __forceinline__ float bf2f(ushort h) {
    union { uint32_t u; float f; } v; v.u = ((uint32_t)h) << 16;
    return v.f;
}

// ---------------- weight transpose: (R,C) fp32 -> (C,R) bf16 ----------------
__global__ __launch_bounds__(256) void k_transpose_bf(const float* __restrict__ in,
        ushort* __restrict__ out, int R, int C) {
    __shared__ float tile[32][33];
    int cb = blockIdx.x * 32, rb = blockIdx.y * 32;
    int tx = threadIdx.x & 31, ty = threadIdx.x >> 5;
    for (int i = ty; i < 32; i += 8) {
        int r = rb + i, c = cb + tx;
        tile[i][tx] = (r < R && c < C) ? in[(size_t)r * C + c] : 0.f;
    }
    __syncthreads();
    for (int i = ty; i < 32; i += 8) {
        int c = cb + i, r = rb + tx;
        if (c < C && r < R) out[(size_t)c * R + r] = f2bf(tile[tx][i]);
    }
}

// ---------------- slots init ----------------
__global__ __launch_bounds__(256) void k_init_slots(const float* __restrict__ noise,
        const float* __restrict__ mu, const float* __restrict__ logsig,
        float* __restrict__ s0) {
    int idx = blockIdx.x * 256 + threadIdx.x;
    int d = idx & 255;
    s0[idx] = mu[d] + expf(logsig[d]) * noise[idx];
}

// ---------------- projection GEMM: xt = x^T @ conv_w + conv_b + pos ----------------
// x: (64,2048,196) fp32, strided-K.  bT: conv_wT (256,2048) bf16 K-contig.
// Tile BM=64, BN=128, BK=64. grid (196, 2). 256 thr = 4 waves (2m x 2n).
__global__ __launch_bounds__(256) void k_proj(const float* __restrict__ x,
        const ushort* __restrict__ bT, const float* __restrict__ cb,
        const float* __restrict__ pos, float* __restrict__ xt) {
    __shared__ ushort As[64 * 64];   // [m][k] swizzled
    __shared__ ushort Bs[128 * 64];  // [n][k] swizzled
    const int t = threadIdx.x;
    const int lane = t & 63;
    const int wv = t >> 6;
    const int wm = wv >> 1, wn = wv & 1;
    const int bm = blockIdx.x * 64;
    const int bn = blockIdx.y * 128;

    const int am = t & 63;
    const int mg = bm + am;
    const int ab = mg / HWN, ap = mg % HWN;
    const float* aptr = x + (size_t)ab * (CIN * HWN) + ap;
    const int achb = t >> 6;           // 0..3

    const int bnl = t >> 1;            // 0..127
    const int bch0 = (t & 1) * 4;
    const ushort* bptr = bT + (size_t)(bn + bnl) * CIN;

    f32x4 acc[2][4] = {};

    for (int k0 = 0; k0 < CIN; k0 += 64) {
        if (k0) __syncthreads();
        // A tile: 16 strided fp32 loads/thread, coalesced across lanes (consecutive m)
        #pragma unroll
        for (int p = 0; p < 2; ++p) {
            int ch = achb + 4 * p;     // 0..7
            short8 av;
            #pragma unroll
            for (int j = 0; j < 8; ++j)
                av[j] = (short)f2bf(aptr[(k0 + ch * 8 + j) * HWN]);
            *(short8*)&As[am * 64 + ((ch ^ (am & 7)) << 3)] = av;
        }
        // B tile: bf16 16B loads (L2-resident conv_wT)
        #pragma unroll
        for (int c = 0; c < 4; ++c) {
            int ch = bch0 + c;
            short8 bv = *(const short8*)&bptr[k0 + ch * 8];
            *(short8*)&Bs[bnl * 64 + ((ch ^ (bnl & 7)) << 3)] = bv;
        }
        __syncthreads();
        #pragma unroll
        for (int kk = 0; kk < 2; ++kk) {
            short8 afr[2], bfr[4];
            #pragma unroll
            for (int mi = 0; mi < 2; ++mi) {
                int row = wm * 32 + mi * 16 + (lane & 15);
                int ch = kk * 4 + (lane >> 4);
                afr[mi] = *(const short8*)&As[row * 64 + ((ch ^ (row & 7)) << 3)];
            }
            #pragma unroll
            for (int ni = 0; ni < 4; ++ni) {
                int row = wn * 64 + ni * 16 + (lane & 15);
                int ch = kk * 4 + (lane >> 4);
                bfr[ni] = *(const short8*)&Bs[row * 64 + ((ch ^ (row & 7)) << 3)];
            }
            #pragma unroll
            for (int mi = 0; mi < 2; ++mi)
                #pragma unroll
                for (int ni = 0; ni < 4; ++ni)
                    acc[mi][ni] = __builtin_amdgcn_mfma_f32_16x16x32_bf16(
                        afr[mi], bfr[ni], acc[mi][ni], 0, 0, 0);
        }
    }
    // epilogue: + conv_b + pos, fp32 out
    #pragma unroll
    for (int mi = 0; mi < 2; ++mi) {
        #pragma unroll
        for (int ni = 0; ni < 4; ++ni) {
            int n = bn + wn * 64 + ni * 16 + (lane & 15);
            float cbn = cb[n];
            #pragma unroll
            for (int r = 0; r < 4; ++r) {
                int row = wm * 32 + mi * 16 + (lane >> 4) * 4 + r;
                int m = bm + row;
                int p = m % HWN;
                xt[(size_t)m * DD + n] = acc[mi][ni][r] + cbn + pos[p * DD + n];
            }
        }
    }
}

// ---------------- LayerNorm over D=256; block=64 threads, one row ----------------
template <int BF16OUT>
__global__ __launch_bounds__(64) void k_ln(const float* __restrict__ in,
        const float* __restrict__ g, const float* __restrict__ b,
        float* __restrict__ outf, ushort* __restrict__ outb) {
    int row = blockIdx.x;
    int l = threadIdx.x;
    f32x4 v = *(const f32x4*)(in + (size_t)row * 256 + l * 4);
    float s  = v[0] + v[1] + v[2] + v[3];
    float ss = v[0]*v[0] + v[1]*v[1] + v[2]*v[2] + v[3]*v[3];
    #pragma unroll
    for (int m = 32; m >= 1; m >>= 1) {
        s  += __shfl_xor(s, m, 64);
        ss += __shfl_xor(ss, m, 64);
    }
    float mean = s * (1.f / 256.f);
    float var  = ss * (1.f / 256.f) - mean * mean;
    float rs = rsqrtf(var + 1e-5f);
    f32x4 gv = *(const f32x4*)&g[l * 4];
    f32x4 bv = *(const f32x4*)&b[l * 4];
    if (BF16OUT) {
        us4 o;
        #pragma unroll
        for (int j = 0; j < 4; ++j)
            o[j] = f2bf((v[j] - mean) * rs * gv[j] + bv[j]);
        *(us4*)&outb[(size_t)row * 256 + l * 4] = o;
    } else {
        f32x4 o;
        #pragma unroll
        for (int j = 0; j < 4; ++j)
            o[j] = (v[j] - mean) * rs * gv[j] + bv[j];
        *(f32x4*)&outf[(size_t)row * 256 + l * 4] = o;
    }
}

// ---------------- k/v GEMM: A (12544,256) bf16 @ BT (256,256) bf16 + bias ----------
// out: padded bf16 (64, NPAD, 256), rows 196..207 untouched (never read).
__global__ __launch_bounds__(256) void k_gemm_kv(const ushort* __restrict__ A,
        const ushort* __restrict__ BT, const float* __restrict__ bias,
        ushort* __restrict__ outp) {
    __shared__ ushort As[64 * 64];
    __shared__ ushort Bs[128 * 64];
    const int t = threadIdx.x, lane = t & 63, wv = t >> 6;
    const int wm = wv >> 1, wn = wv & 1;
    const int bm = blockIdx.x * 64, bn = blockIdx.y * 128;
    const int am = t >> 2;             // 0..63
    const int ach0 = (t & 3) * 2;
    const int bnl = t >> 1;
    const int bch0 = (t & 1) * 4;
    f32x4 acc[2][4] = {};
    for (int k0 = 0; k0 < 256; k0 += 64) {
        if (k0) __syncthreads();
        #pragma unroll
        for (int c = 0; c < 2; ++c) {
            int ch = ach0 + c;
            short8 av = *(const short8*)&A[(size_t)(bm + am) * 256 + k0 + ch * 8];
            *(short8*)&As[am * 64 + ((ch ^ (am & 7)) << 3)] = av;
        }
        #pragma unroll
        for (int c = 0; c < 4; ++c) {
            int ch = bch0 + c;
            short8 bv = *(const short8*)&BT[(size_t)(bn + bnl) * 256 + k0 + ch * 8];
            *(short8*)&Bs[bnl * 64 + ((ch ^ (bnl & 7)) << 3)] = bv;
        }
        __syncthreads();
        #pragma unroll
        for (int kk = 0; kk < 2; ++kk) {
            short8 afr[2], bfr[4];
            #pragma unroll
            for (int mi = 0; mi < 2; ++mi) {
                int row = wm * 32 + mi * 16 + (lane & 15);
                int ch = kk * 4 + (lane >> 4);
                afr[mi] = *(const short8*)&As[row * 64 + ((ch ^ (row & 7)) << 3)];
            }
            #pragma unroll
            for (int ni = 0; ni < 4; ++ni) {
                int row = wn * 64 + ni * 16 + (lane & 15);
                int ch = kk * 4 + (lane >> 4);
                bfr[ni] = *(const short8*)&Bs[row * 64 + ((ch ^ (row & 7)) << 3)];
            }
            #pragma unroll
            for (int mi = 0; mi < 2; ++mi)
                #pragma unroll
                for (int ni = 0; ni < 4; ++ni)
                    acc[mi][ni] = __builtin_amdgcn_mfma_f32_16x16x32_bf16(
                        afr[mi], bfr[ni], acc[mi][ni], 0, 0, 0);
        }
    }
    #pragma unroll
    for (int mi = 0; mi < 2; ++mi) {
        #pragma unroll
        for (int ni = 0; ni < 4; ++ni) {
            int n = bn + wn * 64 + ni * 16 + (lane & 15);
            float bn_ = bias[n];
            #pragma unroll
            for (int r = 0; r < 4; ++r) {
                int row = wm * 32 + mi * 16 + (lane >> 4) * 4 + r;
                int m = bm + row;
                int bq = m / HWN, p = m % HWN;
                outp[((size_t)bq * NPAD + p) * DD + n] = f2bf(acc[mi][ni][r] + bn_);
            }
        }
    }
}

// ---------------- generic fp32 tiled GEMM: C = A(M,K) @ B(K,N) + bias [,relu][,res] ---
template <int RELU, int RES>
__global__ __launch_bounds__(256) void k_gemm_f32(const float* __restrict__ A,
        const float* __restrict__ B, const float* __restrict__ bias,
        const float* __restrict__ res, float* __restrict__ C,
        int M, int N, int K) {
    __shared__ float As[16][68];
    __shared__ float Bs[16][68];
    const int t = threadIdx.x;
    const int tx = t & 15, ty = t >> 4;
    const int bm = blockIdx.y * 64, bn = blockIdx.x * 64;
    float acc[4][4] = {};
    for (int k0 = 0; k0 < K; k0 += 16) {
        if (k0) __syncthreads();
        #pragma unroll
        for (int ps = 0; ps < 4; ++ps) {
            int m = (t >> 4) + ps * 16;
            As[t & 15][m] = A[(size_t)(bm + m) * K + k0 + (t & 15)];
        }
        #pragma unroll
        for (int i = 0; i < 4; ++i) {
            int k = (t >> 6) * 4 + i;
            Bs[k][t & 63] = B[(size_t)(k0 + k) * N + bn + (t & 63)];
        }
        __syncthreads();
        #pragma unroll
        for (int kk = 0; kk < 16; ++kk) {
            f32x4 av = *(const f32x4*)&As[kk][ty * 4];
            f32x4 bv = *(const f32x4*)&Bs[kk][tx * 4];
            #pragma unroll
            for (int i = 0; i < 4; ++i)
                #pragma unroll
                for (int j = 0; j < 4; ++j)
                    acc[i][j] += av[i] * bv[j];
        }
    }
    #pragma unroll
    for (int i = 0; i < 4; ++i) {
        int m = bm + ty * 4 + i;
        #pragma unroll
        for (int j = 0; j < 4; ++j) {
            int n = bn + tx * 4 + j;
            float v = acc[i][j] + bias[n];
            if (RELU) v = fmaxf(v, 0.f);
            if (RES) v += res[(size_t)m * N + n];
            C[(size_t)m * N + n] = v;
        }
    }
}

// ---------------- dots = q . k^T * scale ----------------
__global__ __launch_bounds__(256) void k_dots(const float* __restrict__ q,
        const ushort* __restrict__ kbf, float* __restrict__ dots) {
    __shared__ float qs[256];
    int b = blockIdx.y, i = blockIdx.x, t = threadIdx.x;
    qs[t] = q[(size_t)(b * SS + i) * 256 + t];
    __syncthreads();
    if (t < HWN) {
        const ushort* kr = kbf + ((size_t)b * NPAD + t) * 256;
        float acc = 0.f;
        #pragma unroll 4
        for (int d0 = 0; d0 < 256; d0 += 8) {
            short8 kv = *(const short8*)&kr[d0];
            #pragma unroll
            for (int j = 0; j < 8; ++j)
                acc += qs[d0 + j] * bf2f((ushort)kv[j]);
        }
        dots[(size_t)(b * SS + i) * HWN + t] = acc * 0.0625f;
    }
}

// ---------------- softmax over slots + eps + renorm over keys ----------------
__global__ __launch_bounds__(256) void k_softmax(const float* __restrict__ dots,
        float* __restrict__ attn, float* __restrict__ attn_out) {
    __shared__ float sd[SS][HWN];
    __shared__ float rsum[SS];
    int b = blockIdx.x, t = threadIdx.x;
    for (int idx = t; idx < SS * HWN; idx += 256)
        sd[idx / HWN][idx % HWN] = dots[(size_t)b * SS * HWN + idx];
    __syncthreads();
    if (t < HWN) {
        float mx = sd[0][t];
        #pragma unroll
        for (int i = 1; i < SS; ++i) mx = fmaxf(mx, sd[i][t]);
        float s = 0.f, e[SS];
        #pragma unroll
        for (int i = 0; i < SS; ++i) { e[i] = expf(sd[i][t] - mx); s += e[i]; }
        float inv = 1.f / s;
        #pragma unroll
        for (int i = 0; i < SS; ++i) sd[i][t] = e[i] * inv + 1e-8f;
    }
    __syncthreads();
    if (t < SS) {
        float s = 0.f;
        for (int j = 0; j < HWN; ++j) s += sd[t][j];
        rsum[t] = 1.f / s;
    }
    __syncthreads();
    for (int idx = t; idx < SS * HWN; idx += 256) {
        int i = idx / HWN;
        float v = sd[i][idx % HWN] * rsum[i];
        attn[(size_t)b * SS * HWN + idx] = v;
        attn_out[(size_t)b * SS * HWN + idx] = v;
    }
}

// ---------------- updates = attn @ v ----------------
__global__ __launch_bounds__(256) void k_updates(const float* __restrict__ attn,
        const ushort* __restrict__ vbf, float* __restrict__ upd) {
    __shared__ float as_[HWN];
    int b = blockIdx.y, i = blockIdx.x, t = threadIdx.x;
    if (t < HWN) as_[t] = attn[(size_t)(b * SS + i) * HWN + t];
    __syncthreads();
    float acc = 0.f;
    const ushort* vb = vbf + (size_t)b * NPAD * 256 + t;
    for (int j = 0; j < HWN; ++j)
        acc += as_[j] * bf2f(vb[(size_t)j * 256]);
    upd[(size_t)(b * SS + i) * 256 + t] = acc;
}

// ---------------- GRU gates ----------------
__global__ __launch_bounds__(256) void k_gru_gates(const float* __restrict__ gi,
        const float* __restrict__ gh, const float* __restrict__ sprev,
        float* __restrict__ snew) {
    int idx = blockIdx.x * 256 + threadIdx.x;
    int row = idx >> 8, d = idx & 255;
    float ir = gi[(size_t)row * 768 + d];
    float iz = gi[(size_t)row * 768 + 256 + d];
    float in_ = gi[(size_t)row * 768 + 512 + d];
    float hr = gh[(size_t)row * 768 + d];
    float hz = gh[(size_t)row * 768 + 256 + d];
    float hn = gh[(size_t)row * 768 + 512 + d];
    float r = 1.f / (1.f + expf(-(ir + hr)));
    float z = 1.f / (1.f + expf(-(iz + hz)));
    float nn = tanhf(in_ + r * hn);
    snew[idx] = (1.f - z) * nn + z * sprev[idx];
}

__global__ __launch_bounds__(256) void k_copy(const float* __restrict__ in,
        float* __restrict__ out) {
    int idx = blockIdx.x * 256 + threadIdx.x;
    out[idx] = in[idx];
}

extern "C" void kernel_launch(void* const* d_in, const int* in_sizes, int n_in,
                              void* d_out, int out_size, void* d_ws, size_t ws_size,
                              hipStream_t stream) {
    const float* x      = (const float*)d_in[0];
    const float* noise  = (const float*)d_in[1];
    const float* conv_w = (const float*)d_in[2];
    const float* conv_b = (const float*)d_in[3];
    const float* pos    = (const float*)d_in[4];
    const float* mu     = (const float*)d_in[5];
    const float* logsig = (const float*)d_in[6];
    const float* qw  = (const float*)d_in[7];
    const float* qb  = (const float*)d_in[8];
    const float* kw  = (const float*)d_in[9];
    const float* kb  = (const float*)d_in[10];
    const float* vw  = (const float*)d_in[11];
    const float* vb  = (const float*)d_in[12];
    const float* wih = (const float*)d_in[13];
    const float* whh = (const float*)d_in[14];
    const float* bih = (const float*)d_in[15];
    const float* bhh = (const float*)d_in[16];
    const float* w1  = (const float*)d_in[17];
    const float* b1  = (const float*)d_in[18];
    const float* w2  = (const float*)d_in[19];
    const float* b2  = (const float*)d_in[20];
    const float* g_in = (const float*)d_in[21];
    const float* b_in = (const float*)d_in[22];
    const float* g_s  = (const float*)d_in[23];
    const float* b_s  = (const float*)d_in[24];
    const float* g_ff = (const float*)d_in[25];
    const float* b_ff = (const float*)d_in[26];

    char* w = (char*)d_ws;
    float*  xt     = (float*)w;  w += (size_t)12544 * 256 * 4;
    ushort* inp_bf = (ushort*)w; w += (size_t)12544 * 256 * 2;
    ushort* kbf    = (ushort*)w; w += (size_t)64 * NPAD * 256 * 2;
    ushort* vbf    = (ushort*)w; w += (size_t)64 * NPAD * 256 * 2;
    ushort* cwT    = (ushort*)w; w += (size_t)256 * 2048 * 2;
    ushort* kwT    = (ushort*)w; w += (size_t)256 * 256 * 2;
    ushort* vwT    = (ushort*)w; w += (size_t)256 * 256 * 2;
    float* S0   = (float*)w; w += (size_t)131072 * 4;
    float* S1   = (float*)w; w += (size_t)131072 * 4;
    float* sb   = (float*)w; w += (size_t)131072 * 4;
    float* qbuf = (float*)w; w += (size_t)131072 * 4;
    float* dots = (float*)w; w += (size_t)100352 * 4;
    float* attn = (float*)w; w += (size_t)100352 * 4;
    float* upd  = (float*)w; w += (size_t)131072 * 4;
    float* gi   = (float*)w; w += (size_t)393216 * 4;
    float* gh   = (float*)w; w += (size_t)393216 * 4;
    float* ffb  = (float*)w; w += (size_t)131072 * 4;
    float* hbuf = (float*)w; w += (size_t)262144 * 4;

    float* out_slots = (float*)d_out;
    float* out_attn  = (float*)d_out + 131072;

    k_transpose_bf<<<dim3(8, 64), 256, 0, stream>>>(conv_w, cwT, 2048, 256);
    k_transpose_bf<<<dim3(8, 8), 256, 0, stream>>>(kw, kwT, 256, 256);
    k_transpose_bf<<<dim3(8, 8), 256, 0, stream>>>(vw, vwT, 256, 256);
    k_init_slots<<<512, 256, 0, stream>>>(noise, mu, logsig, S0);
    k_proj<<<dim3(196, 2), 256, 0, stream>>>(x, cwT, conv_b, pos, xt);
    k_ln<1><<<12544, 64, 0, stream>>>(xt, g_in, b_in, nullptr, inp_bf);
    k_gemm_kv<<<dim3(196, 2), 256, 0, stream>>>(inp_bf, kwT, kb, kbf);
    k_gemm_kv<<<dim3(196, 2), 256, 0, stream>>>(inp_bf, vwT, vb, vbf);

    for (int it = 0; it < 3; ++it) {
        k_ln<0><<<512, 64, 0, stream>>>(S0, g_s, b_s, sb, nullptr);
        k_gemm_f32<0,0><<<dim3(4, 8), 256, 0, stream>>>(sb, qw, qb, nullptr, qbuf, 512, 256, 256);
        k_dots<<<dim3(8, 64), 256, 0, stream>>>(qbuf, kbf, dots);
        k_softmax<<<64, 256, 0, stream>>>(dots, attn, out_attn);
        k_updates<<<dim3(8, 64), 256, 0, stream>>>(attn, vbf, upd);
        k_gemm_f32<0,0><<<dim3(12, 8), 256, 0, stream>>>(upd, wih, bih, nullptr, gi, 512, 768, 256);
        k_gemm_f32<0,0><<<dim3(12, 8), 256, 0, stream>>>(S0, whh, bhh, nullptr, gh, 512, 768, 256);
        k_gru_gates<<<512, 256, 0, stream>>>(gi, gh, S0, S1);
        k_ln<0><<<512, 64, 0, stream>>>(S1, g_ff, b_ff, ffb, nullptr);
        k_gemm_f32<1,0><<<dim3(8, 8), 256, 0, stream>>>(ffb, w1, b1, nullptr, hbuf, 512, 512, 256);
        k_gemm_f32<0,1><<<dim3(4, 8), 256, 0, stream>>>(hbuf, w2, b2, S1, S0, 512, 256, 512);
    }
    k_copy<<<512, 256, 0, stream>>>(S0, out_slots);
}

// Round 3
// 348.628 us; speedup vs baseline: 1.3086x; 1.3086x over previous
//
#include <hip/hip_runtime.h>
#include <stdint.h>

#define HWN 196      // tokens
#define CIN 2048     // input channels
#define DD  256      // slot dim
#define BB  64       // batch
#define NSLOT 8      // slots
#define PPAD 256     // token pad in inp_bf (per batch)
#define KVPAD 224    // key pad in kbf / vT

typedef __attribute__((ext_vector_type(8))) short short8;
typedef __attribute__((ext_vector_type(4))) float f32x4;
typedef __attribute__((ext_vector_type(4))) unsigned short us4;

__device__ __forceinline__ ushort f2bf(float f){ union{float f;uint32_t u;}v;v.f=f;uint32_t u=v.u;return (ushort)((u+0x7FFFu+((u>>16)&1u))>>16);}
__device__ __forceinline__ float bf2f(ushort h){ union{uint32_t u;float f;}v;v.u=((uint32_t)h)<<16;return v.f;}

// ======================= weight transposes (one kernel) =======================
struct TD { const float* s; ushort* d; int R, C, t0; };
struct TD8 { TD a[8]; };

__global__ __launch_bounds__(256) void k_prep(TD8 td){
    __shared__ float tile[32][33];
    int bt = blockIdx.x;
    int mi = 0;
    #pragma unroll
    for (int i = 1; i < 8; ++i) if (bt >= td.a[i].t0) mi = i;
    TD d = td.a[mi];
    int lt = bt - d.t0;
    int tilesx = (d.C + 31) >> 5;
    int cb = (lt % tilesx) * 32, rb = (lt / tilesx) * 32;
    int tx = threadIdx.x & 31, ty = threadIdx.x >> 5;
    for (int i = ty; i < 32; i += 8) {
        int r = rb + i, c = cb + tx;
        tile[i][tx] = (r < d.R && c < d.C) ? d.s[(size_t)r * d.C + c] : 0.f;
    }
    __syncthreads();
    for (int i = ty; i < 32; i += 8) {
        int c = cb + i, r = rb + tx;
        if (c < d.C && r < d.R) d.d[(size_t)c * d.R + r] = f2bf(tile[tx][i]);
    }
}

// ======================= projection + pos + LN(ln_in) fused =======================
__global__ __launch_bounds__(512) void k_proj(const float* __restrict__ x,
        const ushort* __restrict__ bT, const float* __restrict__ cb,
        const float* __restrict__ pos, const float* __restrict__ lng,
        const float* __restrict__ lnb, ushort* __restrict__ inp){
    __shared__ ushort As[2][64*64];
    __shared__ ushort Bs[2][256*64];
    __shared__ float lnpart[64][4][2];
    __shared__ float lnstat[64][2];
    const int t = threadIdx.x, lane = t & 63, wv = t >> 6;
    const int wm = wv >> 2, wn = wv & 3;
    const int b = blockIdx.x >> 2;
    const int p0 = (blockIdx.x & 3) * 64;

    const int am = t & 63, akg = t >> 6;
    const int ap = p0 + am;
    const bool aval = ap < HWN;
    const float* aptr = x + ((size_t)b * CIN) * HWN + ap;

    f32x4 acc[2][4] = {};
    float areg[8];
    short8 breg[4];

    #pragma unroll
    for (int j = 0; j < 8; ++j) areg[j] = aval ? aptr[(size_t)(akg*8+j)*HWN] : 0.f;
    #pragma unroll
    for (int p = 0; p < 4; ++p){
        int idx = p*512 + t; int n = idx>>3, ch = idx&7;
        breg[p] = *(const short8*)&bT[(size_t)n*CIN + ch*8];
    }
    {
        short8 av;
        #pragma unroll
        for (int j = 0; j < 8; ++j) av[j] = (short)f2bf(areg[j]);
        *(short8*)&As[0][am*64 + ((akg^(am&7))<<3)] = av;
        #pragma unroll
        for (int p = 0; p < 4; ++p){
            int idx = p*512 + t; int n = idx>>3, ch = idx&7;
            *(short8*)&Bs[0][n*64 + ((ch^(n&7))<<3)] = breg[p];
        }
    }
    __syncthreads();
    int cur = 0;
    for (int kt = 0; kt < 32; ++kt){
        int k0n = (kt+1)*64;
        if (kt < 31){
            #pragma unroll
            for (int j = 0; j < 8; ++j) areg[j] = aval ? aptr[(size_t)(k0n + akg*8+j)*HWN] : 0.f;
            #pragma unroll
            for (int p = 0; p < 4; ++p){
                int idx = p*512 + t; int n = idx>>3, ch = idx&7;
                breg[p] = *(const short8*)&bT[(size_t)n*CIN + k0n + ch*8];
            }
        }
        #pragma unroll
        for (int kk = 0; kk < 2; ++kk){
            short8 afr[2], bfr[4];
            #pragma unroll
            for (int mi = 0; mi < 2; ++mi){
                int row = wm*32 + mi*16 + (lane&15);
                int ch = kk*4 + (lane>>4);
                afr[mi] = *(const short8*)&As[cur][row*64 + ((ch^(row&7))<<3)];
            }
            #pragma unroll
            for (int ni = 0; ni < 4; ++ni){
                int row = wn*64 + ni*16 + (lane&15);
                int ch = kk*4 + (lane>>4);
                bfr[ni] = *(const short8*)&Bs[cur][row*64 + ((ch^(row&7))<<3)];
            }
            #pragma unroll
            for (int mi = 0; mi < 2; ++mi)
                #pragma unroll
                for (int ni = 0; ni < 4; ++ni)
                    acc[mi][ni] = __builtin_amdgcn_mfma_f32_16x16x32_bf16(afr[mi], bfr[ni], acc[mi][ni], 0,0,0);
        }
        if (kt < 31){
            short8 av;
            #pragma unroll
            for (int j = 0; j < 8; ++j) av[j] = (short)f2bf(areg[j]);
            *(short8*)&As[cur^1][am*64 + ((akg^(am&7))<<3)] = av;
            #pragma unroll
            for (int p = 0; p < 4; ++p){
                int idx = p*512 + t; int n = idx>>3, ch = idx&7;
                *(short8*)&Bs[cur^1][n*64 + ((ch^(n&7))<<3)] = breg[p];
            }
        }
        __syncthreads();
        cur ^= 1;
    }
    #pragma unroll
    for (int mi = 0; mi < 2; ++mi){
        #pragma unroll
        for (int r = 0; r < 4; ++r){
            int row = wm*32 + mi*16 + (lane>>4)*4 + r;
            int p = p0 + row;
            float s = 0.f, ss = 0.f;
            #pragma unroll
            for (int ni = 0; ni < 4; ++ni){
                int n = wn*64 + ni*16 + (lane&15);
                float v = 0.f;
                if (p < HWN) v = acc[mi][ni][r] + cb[n] + pos[(size_t)p*DD + n];
                acc[mi][ni][r] = v;
                s += v; ss += v*v;
            }
            #pragma unroll
            for (int m = 8; m >= 1; m >>= 1){ s += __shfl_xor(s, m, 64); ss += __shfl_xor(ss, m, 64); }
            if ((lane & 15) == 0){ lnpart[row][wn][0] = s; lnpart[row][wn][1] = ss; }
        }
    }
    __syncthreads();
    if (t < 64){
        float lsum = 0.f, lsumsq = 0.f;
        #pragma unroll
        for (int i = 0; i < 4; ++i){ lsum += lnpart[t][i][0]; lsumsq += lnpart[t][i][1]; }
        float mean = lsum * (1.f/256.f);
        float var = lsumsq * (1.f/256.f) - mean*mean;
        lnstat[t][0] = mean; lnstat[t][1] = rsqrtf(var + 1e-5f);
    }
    __syncthreads();
    #pragma unroll
    for (int mi = 0; mi < 2; ++mi){
        #pragma unroll
        for (int ni = 0; ni < 4; ++ni){
            int n = wn*64 + ni*16 + (lane&15);
            float gn = lng[n], bn = lnb[n];
            #pragma unroll
            for (int r = 0; r < 4; ++r){
                int row = wm*32 + mi*16 + (lane>>4)*4 + r;
                float o = (acc[mi][ni][r] - lnstat[row][0]) * lnstat[row][1] * gn + bn;
                inp[((size_t)b*PPAD + p0 + row)*DD + n] = f2bf(o);
            }
        }
    }
}

// ======================= fused k & v GEMM (v written transposed) =======================
__global__ __launch_bounds__(512) void k_kv(const ushort* __restrict__ inp,
        const ushort* __restrict__ kwT, const ushort* __restrict__ vwT,
        const float* __restrict__ kb, const float* __restrict__ vb,
        ushort* __restrict__ kbf, ushort* __restrict__ vT){
    __shared__ ushort As[32*256];
    const int t = threadIdx.x, lane = t & 63, wv = t >> 6;
    const int b = blockIdx.x / 7, pblk = blockIdx.x % 7;
    const ushort* arow = inp + ((size_t)b*PPAD + pblk*32)*DD;
    #pragma unroll
    for (int p = 0; p < 2; ++p){
        int idx = p*512 + t; int row = idx>>5, ch = idx&31;
        short8 v = *(const short8*)&arow[(size_t)row*DD + ch*8];
        *(short8*)&As[row*256 + ((ch^(row&7))<<3)] = v;
    }
    __syncthreads();
    f32x4 acck[2][2] = {}, accv[2][2] = {};
    const int n0 = wv*32;
    #pragma unroll
    for (int kt = 0; kt < 8; ++kt){
        short8 afr[2];
        #pragma unroll
        for (int mi = 0; mi < 2; ++mi){
            int row = mi*16 + (lane&15);
            int ch = kt*4 + (lane>>4);
            afr[mi] = *(const short8*)&As[row*256 + ((ch^(row&7))<<3)];
        }
        #pragma unroll
        for (int ni = 0; ni < 2; ++ni){
            int n = n0 + ni*16 + (lane&15);
            int koff = kt*32 + (lane>>4)*8;
            short8 bk = *(const short8*)&kwT[(size_t)n*DD + koff];
            short8 bv = *(const short8*)&vwT[(size_t)n*DD + koff];
            #pragma unroll
            for (int mi = 0; mi < 2; ++mi){
                acck[mi][ni] = __builtin_amdgcn_mfma_f32_16x16x32_bf16(afr[mi], bk, acck[mi][ni],0,0,0);
                accv[mi][ni] = __builtin_amdgcn_mfma_f32_16x16x32_bf16(afr[mi], bv, accv[mi][ni],0,0,0);
            }
        }
    }
    #pragma unroll
    for (int mi = 0; mi < 2; ++mi){
        #pragma unroll
        for (int ni = 0; ni < 2; ++ni){
            int n = n0 + ni*16 + (lane&15);
            float kbn = kb[n], vbn = vb[n];
            int pl0 = pblk*32 + mi*16 + (lane>>4)*4;
            us4 pk;
            #pragma unroll
            for (int r = 0; r < 4; ++r){
                kbf[((size_t)b*KVPAD + pl0 + r)*DD + n] = f2bf(acck[mi][ni][r] + kbn);
                pk[r] = f2bf(accv[mi][ni][r] + vbn);
            }
            *(us4*)&vT[((size_t)b*DD + n)*KVPAD + pl0] = pk;
        }
    }
}

// ======================= fused 3-iteration slot-attention loop =======================
template<int NF, int KT, int ACH>
__device__ __forceinline__ void gemm_rowA(const ushort* __restrict__ A,
        const ushort* __restrict__ Bg, int n0, int ldb, int lane, f32x4* acc){
    #pragma unroll
    for (int kt = 0; kt < KT; ++kt){
        int row = lane & 15;
        int ch = kt*4 + (lane>>4);
        short8 a = *(const short8*)&A[row*(ACH*8) + ((ch^(row&7))<<3)];
        #pragma unroll
        for (int ni = 0; ni < NF; ++ni){
            int n = n0 + ni*16 + (lane&15);
            short8 bfr = *(const short8*)&Bg[(size_t)n*ldb + kt*32 + (lane>>4)*8];
            acc[ni] = __builtin_amdgcn_mfma_f32_16x16x32_bf16(a, bfr, acc[ni], 0,0,0);
        }
    }
}

__device__ __forceinline__ void ln_stage(const float* rowf, const float* g, const float* bb,
        ushort* dst, int row, int lane){
    f32x4 v = *(const f32x4*)&rowf[lane*4];
    float s = v[0]+v[1]+v[2]+v[3];
    float ss = v[0]*v[0]+v[1]*v[1]+v[2]*v[2]+v[3]*v[3];
    #pragma unroll
    for (int m = 32; m >= 1; m >>= 1){ s += __shfl_xor(s, m, 64); ss += __shfl_xor(ss, m, 64); }
    float mean = s * (1.f/256.f);
    float rs = rsqrtf(ss*(1.f/256.f) - mean*mean + 1e-5f);
    f32x4 gv = *(const f32x4*)&g[lane*4];
    f32x4 bv = *(const f32x4*)&bb[lane*4];
    us4 o;
    #pragma unroll
    for (int j = 0; j < 4; ++j) o[j] = f2bf((v[j]-mean)*rs*gv[j] + bv[j]);
    int ch = lane>>1, half = lane&1;
    *(us4*)&dst[row*256 + ((ch^(row&7))<<3) + half*4] = o;
}

__global__ __launch_bounds__(512) void k_iter(
        const float* __restrict__ noise, const float* __restrict__ mu, const float* __restrict__ lsig,
        const ushort* __restrict__ qwT, const float* __restrict__ qb,
        const ushort* __restrict__ kbf, const ushort* __restrict__ vT,
        const ushort* __restrict__ wihT, const ushort* __restrict__ whhT,
        const float* __restrict__ bih, const float* __restrict__ bhh,
        const ushort* __restrict__ w1T, const float* __restrict__ b1,
        const ushort* __restrict__ w2T, const float* __restrict__ b2,
        const float* __restrict__ gs, const float* __restrict__ bs,
        const float* __restrict__ gf, const float* __restrict__ bf_,
        float* __restrict__ out_slots, float* __restrict__ out_attn){
    __shared__ float slots[8][256];
    __shared__ float snew[8][256];
    __shared__ float dots_[8][KVPAD];
    __shared__ float gg[8][768];
    __shared__ float gh_[8][768];
    __shared__ ushort Asb[16*256];
    __shared__ ushort Asl[16*256];
    __shared__ ushort Aq[16*256];
    __shared__ ushort Aup[16*256];
    __shared__ ushort Aat[16*256];
    __shared__ ushort Ahb[16*512];
    const int t = threadIdx.x, lane = t & 63, wv = t >> 6;
    const int b = blockIdx.x;

    for (int i = t; i < 16*256; i += 512){
        if (i >= 8*256){ Asb[i] = 0; Asl[i] = 0; }
        Aat[i] = 0;
    }
    {
        int d4 = lane*4;
        f32x4 nz = *(const f32x4*)&noise[((size_t)b*NSLOT + wv)*DD + d4];
        f32x4 o;
        #pragma unroll
        for (int j = 0; j < 4; ++j) o[j] = mu[d4+j] + expf(lsig[d4+j])*nz[j];
        *(f32x4*)&slots[wv][d4] = o;
    }
    __syncthreads();

    for (int it = 0; it < 3; ++it){
        if (t < 256){
            int row = t>>5, ch = t&31;
            short8 o;
            #pragma unroll
            for (int j = 0; j < 8; ++j) o[j] = (short)f2bf(slots[row][ch*8+j]);
            *(short8*)&Asl[row*256 + ((ch^(row&7))<<3)] = o;
        }
        ln_stage(slots[wv], gs, bs, Asb, wv, lane);
        __syncthreads();
        {
            f32x4 acc[2] = {};
            gemm_rowA<2,8,32>(Asb, qwT, wv*32, 256, lane, acc);
            #pragma unroll
            for (int ni = 0; ni < 2; ++ni){
                int n = wv*32 + ni*16 + (lane&15);
                float qbn = qb[n];
                #pragma unroll
                for (int r = 0; r < 4; ++r){
                    int row = (lane>>4)*4 + r;
                    int ch = n>>3;
                    Aq[row*256 + ((ch^(row&7))<<3) + (n&7)] = f2bf((acc[ni][r]+qbn)*0.0625f);
                }
            }
        }
        __syncthreads();
        #pragma unroll
        for (int rep = 0; rep < 2; ++rep){
            int tile = wv + rep*8;
            if (tile < 14){
                f32x4 acc[1] = {};
                gemm_rowA<1,8,32>(Aq, kbf + (size_t)b*KVPAD*DD, tile*16, 256, lane, acc);
                if ((lane>>4) < 2){
                    #pragma unroll
                    for (int r = 0; r < 4; ++r)
                        dots_[(lane>>4)*4 + r][tile*16 + (lane&15)] = acc[0][r];
                }
            }
        }
        __syncthreads();
        if (t < KVPAD){
            if (t < HWN){
                float mx = dots_[0][t];
                #pragma unroll
                for (int i = 1; i < 8; ++i) mx = fmaxf(mx, dots_[i][t]);
                float s = 0.f, e[8];
                #pragma unroll
                for (int i = 0; i < 8; ++i){ e[i] = expf(dots_[i][t]-mx); s += e[i]; }
                float inv = 1.f/s;
                #pragma unroll
                for (int i = 0; i < 8; ++i) dots_[i][t] = e[i]*inv + 1e-8f;
            } else {
                #pragma unroll
                for (int i = 0; i < 8; ++i) dots_[i][t] = 0.f;
            }
        }
        __syncthreads();
        {
            float s = dots_[wv][lane] + dots_[wv][lane+64] + dots_[wv][lane+128]
                    + (lane < 32 ? dots_[wv][lane+192] : 0.f);
            #pragma unroll
            for (int m = 32; m >= 1; m >>= 1) s += __shfl_xor(s, m, 64);
            float inv = 1.f/s;
            #pragma unroll
            for (int c = 0; c < 4; ++c){
                int key = c*64 + lane;
                if (key < KVPAD){
                    float v = dots_[wv][key]*inv;
                    int ch = key>>3;
                    Aat[wv*256 + ((ch^(wv&7))<<3) + (key&7)] = f2bf(v);
                    if (it == 2 && key < HWN) out_attn[((size_t)b*NSLOT + wv)*HWN + key] = v;
                }
            }
        }
        __syncthreads();
        {
            f32x4 acc[2] = {};
            gemm_rowA<2,7,32>(Aat, vT + (size_t)b*DD*KVPAD, wv*32, KVPAD, lane, acc);
            #pragma unroll
            for (int ni = 0; ni < 2; ++ni){
                int n = wv*32 + ni*16 + (lane&15);
                #pragma unroll
                for (int r = 0; r < 4; ++r){
                    int row = (lane>>4)*4 + r;
                    int ch = n>>3;
                    Aup[row*256 + ((ch^(row&7))<<3) + (n&7)] = f2bf(acc[ni][r]);
                }
            }
        }
        __syncthreads();
        {
            f32x4 ai[6] = {}, ah[6] = {};
            gemm_rowA<6,8,32>(Aup, wihT, wv*96, 256, lane, ai);
            gemm_rowA<6,8,32>(Asl, whhT, wv*96, 256, lane, ah);
            if ((lane>>4) < 2){
                #pragma unroll
                for (int ni = 0; ni < 6; ++ni){
                    int n = wv*96 + ni*16 + (lane&15);
                    float bi = bih[n], bh = bhh[n];
                    #pragma unroll
                    for (int r = 0; r < 4; ++r){
                        int srow = (lane>>4)*4 + r;
                        gg[srow][n]  = ai[ni][r] + bi;
                        gh_[srow][n] = ah[ni][r] + bh;
                    }
                }
            }
        }
        __syncthreads();
        for (int i = t; i < 8*256; i += 512){
            int row = i>>8, d = i&255;
            float ir = gg[row][d], iz = gg[row][256+d], in_ = gg[row][512+d];
            float hr = gh_[row][d], hz = gh_[row][256+d], hn = gh_[row][512+d];
            float r = 1.f/(1.f+expf(-(ir+hr)));
            float z = 1.f/(1.f+expf(-(iz+hz)));
            float nn = tanhf(in_ + r*hn);
            snew[row][d] = (1.f-z)*nn + z*slots[row][d];
        }
        __syncthreads();
        ln_stage(snew[wv], gf, bf_, Asb, wv, lane);
        __syncthreads();
        {
            f32x4 acc[4] = {};
            gemm_rowA<4,8,32>(Asb, w1T, wv*64, 256, lane, acc);
            #pragma unroll
            for (int ni = 0; ni < 4; ++ni){
                int n = wv*64 + ni*16 + (lane&15);
                float b1n = b1[n];
                #pragma unroll
                for (int r = 0; r < 4; ++r){
                    int row = (lane>>4)*4 + r;
                    float v = fmaxf(acc[ni][r]+b1n, 0.f);
                    int ch = n>>3;
                    Ahb[row*512 + ((ch^(row&7))<<3) + (n&7)] = f2bf(v);
                }
            }
        }
        __syncthreads();
        {
            f32x4 acc[2] = {};
            gemm_rowA<2,16,64>(Ahb, w2T, wv*32, 512, lane, acc);
            if ((lane>>4) < 2){
                #pragma unroll
                for (int ni = 0; ni < 2; ++ni){
                    int n = wv*32 + ni*16 + (lane&15);
                    float b2n = b2[n];
                    #pragma unroll
                    for (int r = 0; r < 4; ++r){
                        int srow = (lane>>4)*4 + r;
                        slots[srow][n] = snew[srow][n] + acc[ni][r] + b2n;
                    }
                }
            }
        }
        __syncthreads();
    }
    for (int i = t; i < 8*256; i += 512){
        int row = i>>8, d = i&255;
        out_slots[((size_t)b*NSLOT + row)*DD + d] = slots[row][d];
    }
}

extern "C" void kernel_launch(void* const* d_in, const int* in_sizes, int n_in,
                              void* d_out, int out_size, void* d_ws, size_t ws_size,
                              hipStream_t stream) {
    const float* x      = (const float*)d_in[0];
    const float* noise  = (const float*)d_in[1];
    const float* conv_w = (const float*)d_in[2];
    const float* conv_b = (const float*)d_in[3];
    const float* pos    = (const float*)d_in[4];
    const float* mu     = (const float*)d_in[5];
    const float* logsig = (const float*)d_in[6];
    const float* qw  = (const float*)d_in[7];
    const float* qb  = (const float*)d_in[8];
    const float* kw  = (const float*)d_in[9];
    const float* kb  = (const float*)d_in[10];
    const float* vw  = (const float*)d_in[11];
    const float* vb  = (const float*)d_in[12];
    const float* wih = (const float*)d_in[13];
    const float* whh = (const float*)d_in[14];
    const float* bih = (const float*)d_in[15];
    const float* bhh = (const float*)d_in[16];
    const float* w1  = (const float*)d_in[17];
    const float* b1  = (const float*)d_in[18];
    const float* w2  = (const float*)d_in[19];
    const float* b2  = (const float*)d_in[20];
    const float* g_in = (const float*)d_in[21];
    const float* b_in = (const float*)d_in[22];
    const float* g_s  = (const float*)d_in[23];
    const float* b_s  = (const float*)d_in[24];
    const float* g_ff = (const float*)d_in[25];
    const float* b_ff = (const float*)d_in[26];

    char* w = (char*)d_ws;
    ushort* inp_bf = (ushort*)w; w += (size_t)BB*PPAD*DD*2;
    ushort* kbf    = (ushort*)w; w += (size_t)BB*KVPAD*DD*2;
    ushort* vT     = (ushort*)w; w += (size_t)BB*DD*KVPAD*2;
    ushort* cwT    = (ushort*)w; w += (size_t)DD*CIN*2;
    ushort* qwT    = (ushort*)w; w += (size_t)DD*DD*2;
    ushort* kwT    = (ushort*)w; w += (size_t)DD*DD*2;
    ushort* vwT    = (ushort*)w; w += (size_t)DD*DD*2;
    ushort* wihT   = (ushort*)w; w += (size_t)768*DD*2;
    ushort* whhT   = (ushort*)w; w += (size_t)768*DD*2;
    ushort* w1T    = (ushort*)w; w += (size_t)512*DD*2;
    ushort* w2T    = (ushort*)w; w += (size_t)DD*512*2;

    float* out_slots = (float*)d_out;
    float* out_attn  = (float*)d_out + (size_t)BB*NSLOT*DD;

    TD8 td;
    td.a[0] = { conv_w, cwT, 2048, 256,    0 };
    td.a[1] = { qw,     qwT,  256, 256,  512 };
    td.a[2] = { kw,     kwT,  256, 256,  576 };
    td.a[3] = { vw,     vwT,  256, 256,  640 };
    td.a[4] = { wih,    wihT, 256, 768,  704 };
    td.a[5] = { whh,    whhT, 256, 768,  896 };
    td.a[6] = { w1,     w1T,  256, 512, 1088 };
    td.a[7] = { w2,     w2T,  512, 256, 1216 };

    k_prep<<<1344, 256, 0, stream>>>(td);
    k_proj<<<256, 512, 0, stream>>>(x, cwT, conv_b, pos, g_in, b_in, inp_bf);
    k_kv<<<448, 512, 0, stream>>>(inp_bf, kwT, vwT, kb, vb, kbf, vT);
    k_iter<<<BB, 512, 0, stream>>>(noise, mu, logsig, qwT, qb, kbf, vT,
                                   wihT, whhT, bih, bhh, w1T, b1, w2T, b2,
                                   g_s, b_s, g_ff, b_ff, out_slots, out_attn);
}

// Round 4
// 259.665 us; speedup vs baseline: 1.7569x; 1.3426x over previous
//
#include <hip/hip_runtime.h>
#include <stdint.h>

#define HWN 196      // tokens
#define CIN 2048     // input channels
#define DD  256      // slot dim
#define BB  64       // batch
#define NSLOT 8      // slots
#define PPAD 256     // token pad in inp_bf (per batch)
#define KVPAD 224    // key pad in kbf / vT

typedef __attribute__((ext_vector_type(8))) short short8;
typedef __attribute__((ext_vector_type(4))) float f32x4;
typedef __attribute__((ext_vector_type(4))) unsigned short us4;

__device__ __forceinline__ ushort f2bf(float f){ union{float f;uint32_t u;}v;v.f=f;uint32_t u=v.u;return (ushort)((u+0x7FFFu+((u>>16)&1u))>>16);}
__device__ __forceinline__ float bf2f(ushort h){ union{uint32_t u;float f;}v;v.u=((uint32_t)h)<<16;return v.f;}
__device__ __forceinline__ float sigm(float x){ return 1.f/(1.f+expf(-x)); }

// Y-operand fragment from swizzled LDS [16][LD] (rows = out-col dim, K-contig)
__device__ __forceinline__ short8 ldsY(const ushort* buf, int LD, int kt, int lane){
    int row = lane & 15;
    int ch = kt*4 + (lane>>4);
    return *(const short8*)&buf[row*LD + ((ch ^ (row&7))<<3)];
}
// X-operand fragment from global [*][K] (rows = out-row dim, K-contig)
__device__ __forceinline__ short8 gX(const ushort* base, int K, int nrow, int kt, int lane){
    return *(const short8*)&base[(size_t)nrow*K + kt*32 + (lane>>4)*8];
}

// ======================= weight transposes (one kernel) =======================
struct TD { const float* s; ushort* d; int R, C, t0; };
struct TD8 { TD a[8]; };

__global__ __launch_bounds__(256) void k_prep(TD8 td){
    __shared__ float tile[32][33];
    int bt = blockIdx.x;
    int mi = 0;
    #pragma unroll
    for (int i = 1; i < 8; ++i) if (bt >= td.a[i].t0) mi = i;
    TD d = td.a[mi];
    int lt = bt - d.t0;
    int tilesx = (d.C + 31) >> 5;
    int cb = (lt % tilesx) * 32, rb = (lt / tilesx) * 32;
    int tx = threadIdx.x & 31, ty = threadIdx.x >> 5;
    for (int i = ty; i < 32; i += 8) {
        int r = rb + i, c = cb + tx;
        tile[i][tx] = (r < d.R && c < d.C) ? d.s[(size_t)r * d.C + c] : 0.f;
    }
    __syncthreads();
    for (int i = ty; i < 32; i += 8) {
        int c = cb + i, r = rb + tx;
        if (c < d.C && r < d.R) d.d[(size_t)c * d.R + r] = f2bf(tile[tx][i]);
    }
}

// ======================= projection + pos + LN(ln_in) fused =======================
__global__ __launch_bounds__(512) void k_proj(const float* __restrict__ x,
        const ushort* __restrict__ bT, const float* __restrict__ cb,
        const float* __restrict__ pos, const float* __restrict__ lng,
        const float* __restrict__ lnb, ushort* __restrict__ inp){
    __shared__ ushort As[2][64*64];
    __shared__ ushort Bs[2][256*64];
    __shared__ float lnpart[64][4][2];
    __shared__ float lnstat[64][2];
    const int t = threadIdx.x, lane = t & 63, wv = t >> 6;
    const int wm = wv >> 2, wn = wv & 3;
    const int b = blockIdx.x >> 2;
    const int p0 = (blockIdx.x & 3) * 64;

    const int am = t & 63, akg = t >> 6;
    const int ap = p0 + am;
    const bool aval = ap < HWN;
    const float* aptr = x + ((size_t)b * CIN) * HWN + ap;

    f32x4 acc[2][4] = {};
    float areg[8];
    short8 breg[4];

    #pragma unroll
    for (int j = 0; j < 8; ++j) areg[j] = aval ? aptr[(size_t)(akg*8+j)*HWN] : 0.f;
    #pragma unroll
    for (int p = 0; p < 4; ++p){
        int idx = p*512 + t; int n = idx>>3, ch = idx&7;
        breg[p] = *(const short8*)&bT[(size_t)n*CIN + ch*8];
    }
    {
        short8 av;
        #pragma unroll
        for (int j = 0; j < 8; ++j) av[j] = (short)f2bf(areg[j]);
        *(short8*)&As[0][am*64 + ((akg^(am&7))<<3)] = av;
        #pragma unroll
        for (int p = 0; p < 4; ++p){
            int idx = p*512 + t; int n = idx>>3, ch = idx&7;
            *(short8*)&Bs[0][n*64 + ((ch^(n&7))<<3)] = breg[p];
        }
    }
    __syncthreads();
    int cur = 0;
    for (int kt = 0; kt < 32; ++kt){
        int k0n = (kt+1)*64;
        if (kt < 31){
            #pragma unroll
            for (int j = 0; j < 8; ++j) areg[j] = aval ? aptr[(size_t)(k0n + akg*8+j)*HWN] : 0.f;
            #pragma unroll
            for (int p = 0; p < 4; ++p){
                int idx = p*512 + t; int n = idx>>3, ch = idx&7;
                breg[p] = *(const short8*)&bT[(size_t)n*CIN + k0n + ch*8];
            }
        }
        #pragma unroll
        for (int kk = 0; kk < 2; ++kk){
            short8 afr[2], bfr[4];
            #pragma unroll
            for (int mi = 0; mi < 2; ++mi){
                int row = wm*32 + mi*16 + (lane&15);
                int ch = kk*4 + (lane>>4);
                afr[mi] = *(const short8*)&As[cur][row*64 + ((ch^(row&7))<<3)];
            }
            #pragma unroll
            for (int ni = 0; ni < 4; ++ni){
                int row = wn*64 + ni*16 + (lane&15);
                int ch = kk*4 + (lane>>4);
                bfr[ni] = *(const short8*)&Bs[cur][row*64 + ((ch^(row&7))<<3)];
            }
            #pragma unroll
            for (int mi = 0; mi < 2; ++mi)
                #pragma unroll
                for (int ni = 0; ni < 4; ++ni)
                    acc[mi][ni] = __builtin_amdgcn_mfma_f32_16x16x32_bf16(afr[mi], bfr[ni], acc[mi][ni], 0,0,0);
        }
        if (kt < 31){
            short8 av;
            #pragma unroll
            for (int j = 0; j < 8; ++j) av[j] = (short)f2bf(areg[j]);
            *(short8*)&As[cur^1][am*64 + ((akg^(am&7))<<3)] = av;
            #pragma unroll
            for (int p = 0; p < 4; ++p){
                int idx = p*512 + t; int n = idx>>3, ch = idx&7;
                *(short8*)&Bs[cur^1][n*64 + ((ch^(n&7))<<3)] = breg[p];
            }
        }
        __syncthreads();
        cur ^= 1;
    }
    #pragma unroll
    for (int mi = 0; mi < 2; ++mi){
        #pragma unroll
        for (int r = 0; r < 4; ++r){
            int row = wm*32 + mi*16 + (lane>>4)*4 + r;
            int p = p0 + row;
            float s = 0.f, ss = 0.f;
            #pragma unroll
            for (int ni = 0; ni < 4; ++ni){
                int n = wn*64 + ni*16 + (lane&15);
                float v = 0.f;
                if (p < HWN) v = acc[mi][ni][r] + cb[n] + pos[(size_t)p*DD + n];
                acc[mi][ni][r] = v;
                s += v; ss += v*v;
            }
            #pragma unroll
            for (int m = 8; m >= 1; m >>= 1){ s += __shfl_xor(s, m, 64); ss += __shfl_xor(ss, m, 64); }
            if ((lane & 15) == 0){ lnpart[row][wn][0] = s; lnpart[row][wn][1] = ss; }
        }
    }
    __syncthreads();
    if (t < 64){
        float lsum = 0.f, lsumsq = 0.f;
        #pragma unroll
        for (int i = 0; i < 4; ++i){ lsum += lnpart[t][i][0]; lsumsq += lnpart[t][i][1]; }
        float mean = lsum * (1.f/256.f);
        float var = lsumsq * (1.f/256.f) - mean*mean;
        lnstat[t][0] = mean; lnstat[t][1] = rsqrtf(var + 1e-5f);
    }
    __syncthreads();
    #pragma unroll
    for (int mi = 0; mi < 2; ++mi){
        #pragma unroll
        for (int ni = 0; ni < 4; ++ni){
            int n = wn*64 + ni*16 + (lane&15);
            float gn = lng[n], bn = lnb[n];
            #pragma unroll
            for (int r = 0; r < 4; ++r){
                int row = wm*32 + mi*16 + (lane>>4)*4 + r;
                float o = (acc[mi][ni][r] - lnstat[row][0]) * lnstat[row][1] * gn + bn;
                inp[((size_t)b*PPAD + p0 + row)*DD + n] = f2bf(o);
            }
        }
    }
}

// ======================= fused k & v GEMM (v written transposed) =======================
__global__ __launch_bounds__(512) void k_kv(const ushort* __restrict__ inp,
        const ushort* __restrict__ kwT, const ushort* __restrict__ vwT,
        const float* __restrict__ kb, const float* __restrict__ vb,
        ushort* __restrict__ kbf, ushort* __restrict__ vT){
    __shared__ ushort As[32*256];
    const int t = threadIdx.x, lane = t & 63, wv = t >> 6;
    const int b = blockIdx.x / 7, pblk = blockIdx.x % 7;
    const ushort* arow = inp + ((size_t)b*PPAD + pblk*32)*DD;
    #pragma unroll
    for (int p = 0; p < 2; ++p){
        int idx = p*512 + t; int row = idx>>5, ch = idx&31;
        short8 v = *(const short8*)&arow[(size_t)row*DD + ch*8];
        *(short8*)&As[row*256 + ((ch^(row&7))<<3)] = v;
    }
    __syncthreads();
    f32x4 acck[2][2] = {}, accv[2][2] = {};
    const int n0 = wv*32;
    #pragma unroll
    for (int kt = 0; kt < 8; ++kt){
        short8 afr[2];
        #pragma unroll
        for (int mi = 0; mi < 2; ++mi){
            int row = mi*16 + (lane&15);
            int ch = kt*4 + (lane>>4);
            afr[mi] = *(const short8*)&As[row*256 + ((ch^(row&7))<<3)];
        }
        #pragma unroll
        for (int ni = 0; ni < 2; ++ni){
            int n = n0 + ni*16 + (lane&15);
            int koff = kt*32 + (lane>>4)*8;
            short8 bk = *(const short8*)&kwT[(size_t)n*DD + koff];
            short8 bv = *(const short8*)&vwT[(size_t)n*DD + koff];
            #pragma unroll
            for (int mi = 0; mi < 2; ++mi){
                acck[mi][ni] = __builtin_amdgcn_mfma_f32_16x16x32_bf16(afr[mi], bk, acck[mi][ni],0,0,0);
                accv[mi][ni] = __builtin_amdgcn_mfma_f32_16x16x32_bf16(afr[mi], bv, accv[mi][ni],0,0,0);
            }
        }
    }
    #pragma unroll
    for (int mi = 0; mi < 2; ++mi){
        #pragma unroll
        for (int ni = 0; ni < 2; ++ni){
            int n = n0 + ni*16 + (lane&15);
            float kbn = kb[n], vbn = vb[n];
            int pl0 = pblk*32 + mi*16 + (lane>>4)*4;
            us4 pk;
            #pragma unroll
            for (int r = 0; r < 4; ++r){
                kbf[((size_t)b*KVPAD + pl0 + r)*DD + n] = f2bf(acck[mi][ni][r] + kbn);
                pk[r] = f2bf(accv[mi][ni][r] + vbn);
            }
            *(us4*)&vT[((size_t)b*DD + n)*KVPAD + pl0] = pk;
        }
    }
}

// ======================= slot init: slots0 + LN_s + q =======================
__global__ __launch_bounds__(512) void k_init(const float* __restrict__ noise,
        const float* __restrict__ mu, const float* __restrict__ lsig,
        const ushort* __restrict__ qwT, const float* __restrict__ qb,
        const float* __restrict__ gs, const float* __restrict__ bs,
        float* __restrict__ slots, ushort* __restrict__ qbuf){
    __shared__ float Sld[16*256];
    __shared__ ushort Ysn[16*256];
    __shared__ float part[8][16][2];
    __shared__ float stats[16][2];
    const int t = threadIdx.x, lane = t & 63, w = t >> 6;
    const int bb = blockIdx.x, rbase = bb*16;
    {
        int row = t>>5, ch = t&31; int d = ch*8;
        f32x4 n0 = *(const f32x4*)&noise[(size_t)(rbase+row)*DD + d];
        f32x4 n1 = *(const f32x4*)&noise[(size_t)(rbase+row)*DD + d + 4];
        f32x4 m0 = *(const f32x4*)&mu[d];
        f32x4 m1 = *(const f32x4*)&mu[d+4];
        f32x4 l0 = *(const f32x4*)&lsig[d];
        f32x4 l1 = *(const f32x4*)&lsig[d+4];
        f32x4 s0, s1;
        #pragma unroll
        for (int j = 0; j < 4; ++j){
            s0[j] = m0[j] + expf(l0[j])*n0[j];
            s1[j] = m1[j] + expf(l1[j])*n1[j];
        }
        *(f32x4*)&slots[(size_t)(rbase+row)*DD + d] = s0;
        *(f32x4*)&slots[(size_t)(rbase+row)*DD + d + 4] = s1;
        *(f32x4*)&Sld[row*256 + d] = s0;
        *(f32x4*)&Sld[row*256 + d + 4] = s1;
    }
    __syncthreads();
    f32x4 sv[2];
    #pragma unroll
    for (int sub = 0; sub < 2; ++sub){
        int d0 = w*32 + sub*16 + (lane>>4)*4;
        sv[sub] = *(const f32x4*)&Sld[(lane&15)*256 + d0];
    }
    {
        float lsum = 0.f, lsq = 0.f;
        #pragma unroll
        for (int sub = 0; sub < 2; ++sub)
            #pragma unroll
            for (int r = 0; r < 4; ++r){ float v = sv[sub][r]; lsum += v; lsq += v*v; }
        lsum += __shfl_xor(lsum, 16, 64); lsum += __shfl_xor(lsum, 32, 64);
        lsq  += __shfl_xor(lsq, 16, 64);  lsq  += __shfl_xor(lsq, 32, 64);
        if (lane < 16){ part[w][lane][0] = lsum; part[w][lane][1] = lsq; }
    }
    __syncthreads();
    if (t < 16){
        float a = 0.f, c = 0.f;
        #pragma unroll
        for (int i = 0; i < 8; ++i){ a += part[i][t][0]; c += part[i][t][1]; }
        float mean = a*(1.f/256.f);
        stats[t][0] = mean;
        stats[t][1] = rsqrtf(c*(1.f/256.f) - mean*mean + 1e-5f);
    }
    __syncthreads();
    {
        int slot = lane&15;
        float mean = stats[slot][0], rs = stats[slot][1];
        #pragma unroll
        for (int sub = 0; sub < 2; ++sub){
            int d0 = w*32 + sub*16 + (lane>>4)*4;
            f32x4 g4 = *(const f32x4*)&gs[d0];
            f32x4 b4 = *(const f32x4*)&bs[d0];
            us4 o;
            #pragma unroll
            for (int r = 0; r < 4; ++r) o[r] = f2bf((sv[sub][r]-mean)*rs*g4[r] + b4[r]);
            int ch = d0>>3;
            *(us4*)&Ysn[slot*256 + ((ch^(slot&7))<<3) + (d0&7)] = o;
        }
    }
    __syncthreads();
    f32x4 qa[2] = {};
    #pragma unroll
    for (int kt = 0; kt < 8; ++kt){
        short8 ysn = ldsY(Ysn, 256, kt, lane);
        #pragma unroll
        for (int sub = 0; sub < 2; ++sub){
            int nrow = w*32 + sub*16 + (lane&15);
            short8 x = gX(qwT, 256, nrow, kt, lane);
            qa[sub] = __builtin_amdgcn_mfma_f32_16x16x32_bf16(x, ysn, qa[sub], 0,0,0);
        }
    }
    #pragma unroll
    for (int sub = 0; sub < 2; ++sub){
        int qd0 = w*32 + sub*16 + (lane>>4)*4;
        f32x4 qb4 = *(const f32x4*)&qb[qd0];
        us4 o;
        #pragma unroll
        for (int r = 0; r < 4; ++r) o[r] = f2bf((qa[sub][r]+qb4[r])*0.0625f);
        *(us4*)&qbuf[(size_t)(rbase+(lane&15))*DD + qd0] = o;
    }
}

// ======================= attention: dots -> softmax -> upd =======================
__global__ __launch_bounds__(256) void k_attn(const ushort* __restrict__ qbuf,
        const ushort* __restrict__ kbf, const ushort* __restrict__ vT,
        ushort* __restrict__ upd, float* __restrict__ out_attn, int writeAttn){
    __shared__ ushort Yq[16*256];
    __shared__ ushort Xat[16*256];
    __shared__ float wpart[4][16];
    __shared__ float invk[16];
    const int t = threadIdx.x, lane = t & 63, w = t >> 6;
    const int b = blockIdx.x;
    {
        int row = t>>5, ch = t&31;
        short8 v = *(const short8*)&qbuf[(size_t)(b*NSLOT+row)*DD + ch*8];
        *(short8*)&Yq[row*256 + ((ch^(row&7))<<3)] = v;
        int row2 = row + 8;
        short8 z;
        #pragma unroll
        for (int j = 0; j < 8; ++j) z[j] = 0;
        *(short8*)&Yq[row2*256 + ((ch^(row2&7))<<3)] = z;
    }
    __syncthreads();
    short8 yf[8];
    #pragma unroll
    for (int kt = 0; kt < 8; ++kt) yf[kt] = ldsY(Yq, 256, kt, lane);
    float ps = 0.f;
    const int nf = (w < 3) ? 4 : 2;            // frags {4,4,4,2} -> 14 key-tiles
    for (int i = 0; i < nf; ++i){
        int f = w*4 + i;
        f32x4 acc = {};
        #pragma unroll
        for (int kt = 0; kt < 8; ++kt){
            short8 x = gX(kbf + (size_t)b*KVPAD*DD, 256, f*16 + (lane&15), kt, lane);
            acc = __builtin_amdgcn_mfma_f32_16x16x32_bf16(x, yf[kt], acc, 0,0,0);
        }
        int k0 = f*16 + (lane>>4)*4;
        us4 o;
        #pragma unroll
        for (int r = 0; r < 4; ++r){
            float v = acc[r];
            float mx = v;
            mx = fmaxf(mx, __shfl_xor(mx, 1, 64));
            mx = fmaxf(mx, __shfl_xor(mx, 2, 64));
            mx = fmaxf(mx, __shfl_xor(mx, 4, 64));
            float e = expf(v - mx);
            float se = e;
            se += __shfl_xor(se, 1, 64);
            se += __shfl_xor(se, 2, 64);
            se += __shfl_xor(se, 4, 64);
            float val = e/se + 1e-8f;
            if (k0 + r >= HWN) val = 0.f;
            ps += val;
            o[r] = f2bf(val);
        }
        int slot = lane & 15;
        int ch = k0 >> 3;
        *(us4*)&Xat[slot*256 + ((ch^(slot&7))<<3) + (k0&7)] = o;
    }
    ps += __shfl_xor(ps, 16, 64);
    ps += __shfl_xor(ps, 32, 64);
    if (lane < 16) wpart[w][lane] = ps;
    __syncthreads();
    if (t < 16) invk[t] = 1.f/(wpart[0][t] + wpart[1][t] + wpart[2][t] + wpart[3][t]);
    __syncthreads();
    short8 xa[7];
    #pragma unroll
    for (int kt = 0; kt < 7; ++kt) xa[kt] = ldsY(Xat, 256, kt, lane);
    #pragma unroll
    for (int i = 0; i < 4; ++i){
        int d0 = (w*4 + i)*16;
        f32x4 acc = {};
        #pragma unroll
        for (int kt = 0; kt < 7; ++kt){
            short8 y = gX(vT + (size_t)b*DD*KVPAD, KVPAD, d0 + (lane&15), kt, lane);
            acc = __builtin_amdgcn_mfma_f32_16x16x32_bf16(xa[kt], y, acc, 0,0,0);
        }
        #pragma unroll
        for (int r = 0; r < 4; ++r){
            int slot = (lane>>4)*4 + r;
            if (slot < NSLOT)
                upd[(size_t)(b*NSLOT+slot)*DD + d0 + (lane&15)] = f2bf(acc[r]*invk[slot]);
        }
    }
    if (writeAttn){
        for (int idx = t; idx < NSLOT*HWN; idx += 256){
            int slot = idx/HWN, key = idx - slot*HWN;
            int ch = key >> 3;
            float v = bf2f(Xat[slot*256 + ((ch^(slot&7))<<3) + (key&7)]);
            out_attn[(size_t)b*NSLOT*HWN + idx] = v*invk[slot];
        }
    }
}

// ======================= row update: GRU + FF + LN_s + next q =======================
__global__ __launch_bounds__(512) void k_upd(
        const ushort* __restrict__ upd, float* __restrict__ slots,
        ushort* __restrict__ qbuf,
        const ushort* __restrict__ wihT, const ushort* __restrict__ whhT,
        const float* __restrict__ bih, const float* __restrict__ bhh,
        const ushort* __restrict__ w1T, const float* __restrict__ b1,
        const ushort* __restrict__ w2T, const float* __restrict__ b2,
        const float* __restrict__ gff, const float* __restrict__ bff,
        const float* __restrict__ gs, const float* __restrict__ bs,
        const ushort* __restrict__ qwT, const float* __restrict__ qb,
        float* __restrict__ out_slots, int final_){
    __shared__ ushort Yupd[16*256];
    __shared__ ushort Yslb[16*256];
    __shared__ ushort Ysn[16*256];
    __shared__ ushort Yh[16*512];
    __shared__ float part[8][16][2];
    __shared__ float stats[16][2];
    const int t = threadIdx.x, lane = t & 63, w = t >> 6;
    const int bb = blockIdx.x, rbase = bb*16;
    {
        int row = t>>5, ch = t&31;
        short8 uv = *(const short8*)&upd[(size_t)(rbase+row)*DD + ch*8];
        *(short8*)&Yupd[row*256 + ((ch^(row&7))<<3)] = uv;
        f32x4 s0 = *(const f32x4*)&slots[(size_t)(rbase+row)*DD + ch*8];
        f32x4 s1 = *(const f32x4*)&slots[(size_t)(rbase+row)*DD + ch*8 + 4];
        short8 sv;
        #pragma unroll
        for (int j = 0; j < 4; ++j){ sv[j] = (short)f2bf(s0[j]); sv[4+j] = (short)f2bf(s1[j]); }
        *(short8*)&Yslb[row*256 + ((ch^(row&7))<<3)] = sv;
    }
    __syncthreads();
    // gi = upd@wih, gh = slots_prev@whh  (out^T: rows = gate-dim, cols = 16 slot-rows)
    f32x4 gi[6] = {}, gh[6] = {};
    #pragma unroll
    for (int kt = 0; kt < 8; ++kt){
        short8 yu = ldsY(Yupd, 256, kt, lane);
        short8 ys = ldsY(Yslb, 256, kt, lane);
        #pragma unroll
        for (int g = 0; g < 3; ++g)
            #pragma unroll
            for (int sub = 0; sub < 2; ++sub){
                int nrow = g*256 + w*32 + sub*16 + (lane&15);
                short8 xi = gX(wihT, 256, nrow, kt, lane);
                short8 xh = gX(whhT, 256, nrow, kt, lane);
                gi[g*2+sub] = __builtin_amdgcn_mfma_f32_16x16x32_bf16(xi, yu, gi[g*2+sub], 0,0,0);
                gh[g*2+sub] = __builtin_amdgcn_mfma_f32_16x16x32_bf16(xh, ys, gh[g*2+sub], 0,0,0);
            }
    }
    // GRU combine (lane-local: gate triplet shares (d, slot) position)
    f32x4 snew[2];
    #pragma unroll
    for (int sub = 0; sub < 2; ++sub){
        int d0 = w*32 + sub*16 + (lane>>4)*4;
        f32x4 sp  = *(const f32x4*)&slots[(size_t)(rbase + (lane&15))*DD + d0];
        f32x4 bir = *(const f32x4*)&bih[d0];
        f32x4 biz = *(const f32x4*)&bih[256 + d0];
        f32x4 bin = *(const f32x4*)&bih[512 + d0];
        f32x4 bhr = *(const f32x4*)&bhh[d0];
        f32x4 bhz = *(const f32x4*)&bhh[256 + d0];
        f32x4 bhn = *(const f32x4*)&bhh[512 + d0];
        #pragma unroll
        for (int r = 0; r < 4; ++r){
            float ir = gi[0+sub][r] + bir[r];
            float iz = gi[2+sub][r] + biz[r];
            float in_ = gi[4+sub][r] + bin[r];
            float hr = gh[0+sub][r] + bhr[r];
            float hz = gh[2+sub][r] + bhz[r];
            float hn = gh[4+sub][r] + bhn[r];
            float rr = sigm(ir + hr);
            float zz = sigm(iz + hz);
            float nn = tanhf(in_ + rr*hn);
            snew[sub][r] = (1.f - zz)*nn + zz*sp[r];
        }
    }
    // LN_ff
    {
        float lsum = 0.f, lsq = 0.f;
        #pragma unroll
        for (int sub = 0; sub < 2; ++sub)
            #pragma unroll
            for (int r = 0; r < 4; ++r){ float v = snew[sub][r]; lsum += v; lsq += v*v; }
        lsum += __shfl_xor(lsum, 16, 64); lsum += __shfl_xor(lsum, 32, 64);
        lsq  += __shfl_xor(lsq, 16, 64);  lsq  += __shfl_xor(lsq, 32, 64);
        if (lane < 16){ part[w][lane][0] = lsum; part[w][lane][1] = lsq; }
    }
    __syncthreads();
    if (t < 16){
        float a = 0.f, c = 0.f;
        #pragma unroll
        for (int i = 0; i < 8; ++i){ a += part[i][t][0]; c += part[i][t][1]; }
        float mean = a*(1.f/256.f);
        stats[t][0] = mean;
        stats[t][1] = rsqrtf(c*(1.f/256.f) - mean*mean + 1e-5f);
    }
    __syncthreads();
    {
        int slot = lane & 15;
        float mean = stats[slot][0], rs = stats[slot][1];
        #pragma unroll
        for (int sub = 0; sub < 2; ++sub){
            int d0 = w*32 + sub*16 + (lane>>4)*4;
            f32x4 g4 = *(const f32x4*)&gff[d0];
            f32x4 b4 = *(const f32x4*)&bff[d0];
            us4 o;
            #pragma unroll
            for (int r = 0; r < 4; ++r) o[r] = f2bf((snew[sub][r]-mean)*rs*g4[r] + b4[r]);
            int ch = d0 >> 3;
            *(us4*)&Ysn[slot*256 + ((ch^(slot&7))<<3) + (d0&7)] = o;
        }
    }
    __syncthreads();
    // ff1: h = relu(snorm @ w1 + b1)
    f32x4 hh[4] = {};
    #pragma unroll
    for (int kt = 0; kt < 8; ++kt){
        short8 ysn = ldsY(Ysn, 256, kt, lane);
        #pragma unroll
        for (int s2 = 0; s2 < 4; ++s2){
            int nrow = w*64 + s2*16 + (lane&15);
            short8 x = gX(w1T, 256, nrow, kt, lane);
            hh[s2] = __builtin_amdgcn_mfma_f32_16x16x32_bf16(x, ysn, hh[s2], 0,0,0);
        }
    }
    {
        int row = lane & 15;
        #pragma unroll
        for (int s2 = 0; s2 < 4; ++s2){
            int n0 = w*64 + s2*16 + (lane>>4)*4;
            f32x4 b14 = *(const f32x4*)&b1[n0];
            us4 o;
            #pragma unroll
            for (int r = 0; r < 4; ++r) o[r] = f2bf(fmaxf(hh[s2][r] + b14[r], 0.f));
            int ch = n0 >> 3;
            *(us4*)&Yh[row*512 + ((ch^(row&7))<<3) + (n0&7)] = o;
        }
    }
    __syncthreads();
    // ff2 + residual
    f32x4 o2[2] = {};
    #pragma unroll
    for (int kt = 0; kt < 16; ++kt){
        short8 yh = ldsY(Yh, 512, kt, lane);
        #pragma unroll
        for (int sub = 0; sub < 2; ++sub){
            int nrow = w*32 + sub*16 + (lane&15);
            short8 x = gX(w2T, 512, nrow, kt, lane);
            o2[sub] = __builtin_amdgcn_mfma_f32_16x16x32_bf16(x, yh, o2[sub], 0,0,0);
        }
    }
    f32x4 ns[2];
    {
        float* dst = final_ ? out_slots : slots;
        #pragma unroll
        for (int sub = 0; sub < 2; ++sub){
            int d0 = w*32 + sub*16 + (lane>>4)*4;
            f32x4 b24 = *(const f32x4*)&b2[d0];
            #pragma unroll
            for (int r = 0; r < 4; ++r) ns[sub][r] = o2[sub][r] + b24[r] + snew[sub][r];
            *(f32x4*)&dst[(size_t)(rbase + (lane&15))*DD + d0] = ns[sub];
        }
    }
    if (final_) return;
    // LN_s + q for next iteration
    {
        float lsum = 0.f, lsq = 0.f;
        #pragma unroll
        for (int sub = 0; sub < 2; ++sub)
            #pragma unroll
            for (int r = 0; r < 4; ++r){ float v = ns[sub][r]; lsum += v; lsq += v*v; }
        lsum += __shfl_xor(lsum, 16, 64); lsum += __shfl_xor(lsum, 32, 64);
        lsq  += __shfl_xor(lsq, 16, 64);  lsq  += __shfl_xor(lsq, 32, 64);
        if (lane < 16){ part[w][lane][0] = lsum; part[w][lane][1] = lsq; }
    }
    __syncthreads();
    if (t < 16){
        float a = 0.f, c = 0.f;
        #pragma unroll
        for (int i = 0; i < 8; ++i){ a += part[i][t][0]; c += part[i][t][1]; }
        float mean = a*(1.f/256.f);
        stats[t][0] = mean;
        stats[t][1] = rsqrtf(c*(1.f/256.f) - mean*mean + 1e-5f);
    }
    __syncthreads();
    {
        int slot = lane & 15;
        float mean = stats[slot][0], rs = stats[slot][1];
        #pragma unroll
        for (int sub = 0; sub < 2; ++sub){
            int d0 = w*32 + sub*16 + (lane>>4)*4;
            f32x4 g4 = *(const f32x4*)&gs[d0];
            f32x4 b4 = *(const f32x4*)&bs[d0];
            us4 o;
            #pragma unroll
            for (int r = 0; r < 4; ++r) o[r] = f2bf((ns[sub][r]-mean)*rs*g4[r] + b4[r]);
            int ch = d0 >> 3;
            *(us4*)&Ysn[slot*256 + ((ch^(slot&7))<<3) + (d0&7)] = o;
        }
    }
    __syncthreads();
    f32x4 qa[2] = {};
    #pragma unroll
    for (int kt = 0; kt < 8; ++kt){
        short8 ysn = ldsY(Ysn, 256, kt, lane);
        #pragma unroll
        for (int sub = 0; sub < 2; ++sub){
            int nrow = w*32 + sub*16 + (lane&15);
            short8 x = gX(qwT, 256, nrow, kt, lane);
            qa[sub] = __builtin_amdgcn_mfma_f32_16x16x32_bf16(x, ysn, qa[sub], 0,0,0);
        }
    }
    #pragma unroll
    for (int sub = 0; sub < 2; ++sub){
        int qd0 = w*32 + sub*16 + (lane>>4)*4;
        f32x4 qb4 = *(const f32x4*)&qb[qd0];
        us4 o;
        #pragma unroll
        for (int r = 0; r < 4; ++r) o[r] = f2bf((qa[sub][r]+qb4[r])*0.0625f);
        *(us4*)&qbuf[(size_t)(rbase+(lane&15))*DD + qd0] = o;
    }
}

extern "C" void kernel_launch(void* const* d_in, const int* in_sizes, int n_in,
                              void* d_out, int out_size, void* d_ws, size_t ws_size,
                              hipStream_t stream) {
    const float* x      = (const float*)d_in[0];
    const float* noise  = (const float*)d_in[1];
    const float* conv_w = (const float*)d_in[2];
    const float* conv_b = (const float*)d_in[3];
    const float* pos    = (const float*)d_in[4];
    const float* mu     = (const float*)d_in[5];
    const float* logsig = (const float*)d_in[6];
    const float* qw  = (const float*)d_in[7];
    const float* qb  = (const float*)d_in[8];
    const float* kw  = (const float*)d_in[9];
    const float* kb  = (const float*)d_in[10];
    const float* vw  = (const float*)d_in[11];
    const float* vb  = (const float*)d_in[12];
    const float* wih = (const float*)d_in[13];
    const float* whh = (const float*)d_in[14];
    const float* bih = (const float*)d_in[15];
    const float* bhh = (const float*)d_in[16];
    const float* w1  = (const float*)d_in[17];
    const float* b1  = (const float*)d_in[18];
    const float* w2  = (const float*)d_in[19];
    const float* b2  = (const float*)d_in[20];
    const float* g_in = (const float*)d_in[21];
    const float* b_in = (const float*)d_in[22];
    const float* g_s  = (const float*)d_in[23];
    const float* b_s  = (const float*)d_in[24];
    const float* g_ff = (const float*)d_in[25];
    const float* b_ff = (const float*)d_in[26];

    char* w = (char*)d_ws;
    ushort* inp_bf = (ushort*)w; w += (size_t)BB*PPAD*DD*2;
    ushort* kbf    = (ushort*)w; w += (size_t)BB*KVPAD*DD*2;
    ushort* vT     = (ushort*)w; w += (size_t)BB*DD*KVPAD*2;
    ushort* cwT    = (ushort*)w; w += (size_t)DD*CIN*2;
    ushort* qwT    = (ushort*)w; w += (size_t)DD*DD*2;
    ushort* kwT    = (ushort*)w; w += (size_t)DD*DD*2;
    ushort* vwT    = (ushort*)w; w += (size_t)DD*DD*2;
    ushort* wihT   = (ushort*)w; w += (size_t)768*DD*2;
    ushort* whhT   = (ushort*)w; w += (size_t)768*DD*2;
    ushort* w1T    = (ushort*)w; w += (size_t)512*DD*2;
    ushort* w2T    = (ushort*)w; w += (size_t)DD*512*2;
    ushort* qbb    = (ushort*)w; w += (size_t)BB*NSLOT*DD*2;
    ushort* updb   = (ushort*)w; w += (size_t)BB*NSLOT*DD*2;
    float*  slotsb = (float*)w;  w += (size_t)BB*NSLOT*DD*4;

    float* out_slots = (float*)d_out;
    float* out_attn  = (float*)d_out + (size_t)BB*NSLOT*DD;

    TD8 td;
    td.a[0] = { conv_w, cwT, 2048, 256,    0 };
    td.a[1] = { qw,     qwT,  256, 256,  512 };
    td.a[2] = { kw,     kwT,  256, 256,  576 };
    td.a[3] = { vw,     vwT,  256, 256,  640 };
    td.a[4] = { wih,    wihT, 256, 768,  704 };
    td.a[5] = { whh,    whhT, 256, 768,  896 };
    td.a[6] = { w1,     w1T,  256, 512, 1088 };
    td.a[7] = { w2,     w2T,  512, 256, 1216 };

    k_prep<<<1344, 256, 0, stream>>>(td);
    k_proj<<<256, 512, 0, stream>>>(x, cwT, conv_b, pos, g_in, b_in, inp_bf);
    k_kv<<<448, 512, 0, stream>>>(inp_bf, kwT, vwT, kb, vb, kbf, vT);
    k_init<<<32, 512, 0, stream>>>(noise, mu, logsig, qwT, qb, g_s, b_s, slotsb, qbb);
    for (int it = 0; it < 3; ++it){
        k_attn<<<64, 256, 0, stream>>>(qbb, kbf, vT, updb, out_attn, it == 2);
        k_upd<<<32, 512, 0, stream>>>(updb, slotsb, qbb, wihT, whhT, bih, bhh,
                                      w1T, b1, w2T, b2, g_ff, b_ff, g_s, b_s,
                                      qwT, qb, out_slots, it == 2);
    }
}

// Round 5
// 243.121 us; speedup vs baseline: 1.8764x; 1.0680x over previous
//
#include <hip/hip_runtime.h>
#include <stdint.h>

#define HWN 196      // tokens
#define CIN 2048     // input channels
#define DD  256      // slot dim
#define BB  64       // batch
#define NSLOT 8      // slots
#define KVPAD 224    // key pad in kbf / vT
#define MTOT 12544   // BB*HWN

typedef __attribute__((ext_vector_type(8))) short short8;
typedef __attribute__((ext_vector_type(4))) float f32x4;
typedef __attribute__((ext_vector_type(4))) unsigned short us4;

__device__ __forceinline__ ushort f2bf(float f){ union{float f;uint32_t u;}v;v.f=f;uint32_t u=v.u;return (ushort)((u+0x7FFFu+((u>>16)&1u))>>16);}
__device__ __forceinline__ float bf2f(ushort h){ union{uint32_t u;float f;}v;v.u=((uint32_t)h)<<16;return v.f;}
__device__ __forceinline__ float sigm(float x){ return 1.f/(1.f+expf(-x)); }

// Y-operand fragment from swizzled LDS [16][LD] (rows = out-col dim, K-contig)
__device__ __forceinline__ short8 ldsY(const ushort* buf, int LD, int kt, int lane){
    int row = lane & 15;
    int ch = kt*4 + (lane>>4);
    return *(const short8*)&buf[row*LD + ((ch ^ (row&7))<<3)];
}
// X-operand fragment from global [*][K] (rows = out-row dim, K-contig)
__device__ __forceinline__ short8 gX(const ushort* base, int K, int nrow, int kt, int lane){
    return *(const short8*)&base[(size_t)nrow*K + kt*32 + (lane>>4)*8];
}

// ======================= weight transposes (one kernel) =======================
struct TD { const float* s; ushort* d; int R, C, t0; };
struct TD8 { TD a[8]; };

__global__ __launch_bounds__(256) void k_prep(TD8 td){
    __shared__ float tile[32][33];
    int bt = blockIdx.x;
    int mi = 0;
    #pragma unroll
    for (int i = 1; i < 8; ++i) if (bt >= td.a[i].t0) mi = i;
    TD d = td.a[mi];
    int lt = bt - d.t0;
    int tilesx = (d.C + 31) >> 5;
    int cb = (lt % tilesx) * 32, rb = (lt / tilesx) * 32;
    int tx = threadIdx.x & 31, ty = threadIdx.x >> 5;
    for (int i = ty; i < 32; i += 8) {
        int r = rb + i, c = cb + tx;
        tile[i][tx] = (r < d.R && c < d.C) ? d.s[(size_t)r * d.C + c] : 0.f;
    }
    __syncthreads();
    for (int i = ty; i < 32; i += 8) {
        int c = cb + i, r = rb + tx;
        if (c < d.C && r < d.R) d.d[(size_t)c * d.R + r] = f2bf(tile[tx][i]);
    }
}

// ======================= projection + pos (NO LN) =======================
// x (64,2048,196) fp32 -> xt (12544,256) bf16 (pos-added).
// BM=64, BN=128, grid (2,196), 512 thr, reg-prefetch + LDS dbuf.
__global__ __launch_bounds__(512) void k_proj(const float* __restrict__ x,
        const ushort* __restrict__ bT, const float* __restrict__ cb,
        const float* __restrict__ pos, ushort* __restrict__ xt){
    __shared__ ushort As[2][64*64];
    __shared__ ushort Bs[2][128*64];
    const int t = threadIdx.x, lane = t & 63, wv = t >> 6;
    const int wm = wv >> 2, wn = wv & 3;
    const int bm = blockIdx.y * 64;
    const int bn = blockIdx.x * 128;

    const int am = t & 63, akg = t >> 6;       // A: m row, k-group (0..7)
    const int mg = bm + am;
    const int ab = mg / HWN, ap = mg % HWN;
    const float* aptr = x + (size_t)ab * (CIN * HWN) + ap;

    const int bnl = t >> 2;                    // 0..127
    const int bch0 = (t & 3) * 2;
    const ushort* bptr = bT + (size_t)(bn + bnl) * CIN;

    f32x4 acc[2][2] = {};
    float areg[8];
    short8 breg[2];

    #pragma unroll
    for (int j = 0; j < 8; ++j) areg[j] = aptr[(size_t)(akg*8+j)*HWN];
    #pragma unroll
    for (int c = 0; c < 2; ++c) breg[c] = *(const short8*)&bptr[(bch0+c)*8];
    {
        short8 av;
        #pragma unroll
        for (int j = 0; j < 8; ++j) av[j] = (short)f2bf(areg[j]);
        *(short8*)&As[0][am*64 + ((akg^(am&7))<<3)] = av;
        #pragma unroll
        for (int c = 0; c < 2; ++c){
            int ch = bch0 + c;
            *(short8*)&Bs[0][bnl*64 + ((ch^(bnl&7))<<3)] = breg[c];
        }
    }
    __syncthreads();
    int cur = 0;
    for (int kt = 0; kt < 32; ++kt){
        int k0n = (kt+1)*64;
        if (kt < 31){
            #pragma unroll
            for (int j = 0; j < 8; ++j) areg[j] = aptr[(size_t)(k0n + akg*8+j)*HWN];
            #pragma unroll
            for (int c = 0; c < 2; ++c) breg[c] = *(const short8*)&bptr[k0n + (bch0+c)*8];
        }
        #pragma unroll
        for (int kk = 0; kk < 2; ++kk){
            short8 afr[2], bfr[2];
            #pragma unroll
            for (int mi = 0; mi < 2; ++mi){
                int row = wm*32 + mi*16 + (lane&15);
                int ch = kk*4 + (lane>>4);
                afr[mi] = *(const short8*)&As[cur][row*64 + ((ch^(row&7))<<3)];
            }
            #pragma unroll
            for (int ni = 0; ni < 2; ++ni){
                int row = wn*32 + ni*16 + (lane&15);
                int ch = kk*4 + (lane>>4);
                bfr[ni] = *(const short8*)&Bs[cur][row*64 + ((ch^(row&7))<<3)];
            }
            #pragma unroll
            for (int mi = 0; mi < 2; ++mi)
                #pragma unroll
                for (int ni = 0; ni < 2; ++ni)
                    acc[mi][ni] = __builtin_amdgcn_mfma_f32_16x16x32_bf16(afr[mi], bfr[ni], acc[mi][ni], 0,0,0);
        }
        if (kt < 31){
            short8 av;
            #pragma unroll
            for (int j = 0; j < 8; ++j) av[j] = (short)f2bf(areg[j]);
            *(short8*)&As[cur^1][am*64 + ((akg^(am&7))<<3)] = av;
            #pragma unroll
            for (int c = 0; c < 2; ++c){
                int ch = bch0 + c;
                *(short8*)&Bs[cur^1][bnl*64 + ((ch^(bnl&7))<<3)] = breg[c];
            }
        }
        __syncthreads();
        cur ^= 1;
    }
    // epilogue: + conv_b + pos, bf16 out
    #pragma unroll
    for (int mi = 0; mi < 2; ++mi){
        #pragma unroll
        for (int ni = 0; ni < 2; ++ni){
            int n = bn + wn*32 + ni*16 + (lane&15);
            float cbn = cb[n];
            #pragma unroll
            for (int r = 0; r < 4; ++r){
                int row = wm*32 + mi*16 + (lane>>4)*4 + r;
                int m = bm + row;
                int p = m % HWN;
                xt[(size_t)m*DD + n] = f2bf(acc[mi][ni][r] + cbn + pos[(size_t)p*DD + n]);
            }
        }
    }
}

// ======================= fused LN + k & v GEMM (v written transposed) =======================
// xt (12544,256) bf16 -> kbf (64,224,256) bf16 ; vT (64,256,224) bf16
__global__ __launch_bounds__(512) void k_kv(const ushort* __restrict__ xt,
        const ushort* __restrict__ kwT, const ushort* __restrict__ vwT,
        const float* __restrict__ kb, const float* __restrict__ vb,
        const float* __restrict__ lng, const float* __restrict__ lnb,
        ushort* __restrict__ kbf, ushort* __restrict__ vT){
    __shared__ ushort As[32*256];
    const int t = threadIdx.x, lane = t & 63, wv = t >> 6;
    const int b = blockIdx.x / 7, pblk = blockIdx.x % 7;
    {   // stage 32 rows with LayerNorm fused. 16 threads per row.
        int row = t >> 4, seg = t & 15;
        int grow = b*HWN + pblk*32 + row;
        if (grow > MTOT-1) grow = MTOT-1;
        const ushort* src = &xt[(size_t)grow*DD + seg*16];
        short8 v0 = *(const short8*)&src[0];
        short8 v1 = *(const short8*)&src[8];
        float f[16];
        #pragma unroll
        for (int j = 0; j < 8; ++j){ f[j] = bf2f((ushort)v0[j]); f[8+j] = bf2f((ushort)v1[j]); }
        float s = 0.f, sq = 0.f;
        #pragma unroll
        for (int j = 0; j < 16; ++j){ s += f[j]; sq += f[j]*f[j]; }
        #pragma unroll
        for (int m = 8; m >= 1; m >>= 1){ s += __shfl_xor(s, m, 64); sq += __shfl_xor(sq, m, 64); }
        float mean = s * (1.f/256.f);
        float rs = rsqrtf(sq*(1.f/256.f) - mean*mean + 1e-5f);
        int d0 = seg*16;
        short8 o0, o1;
        #pragma unroll
        for (int j = 0; j < 8; ++j){
            o0[j] = (short)f2bf((f[j]   - mean)*rs*lng[d0+j]   + lnb[d0+j]);
            o1[j] = (short)f2bf((f[8+j] - mean)*rs*lng[d0+8+j] + lnb[d0+8+j]);
        }
        int ch0 = seg*2;
        *(short8*)&As[row*256 + ((ch0^(row&7))<<3)] = o0;
        *(short8*)&As[row*256 + (((ch0+1)^(row&7))<<3)] = o1;
    }
    __syncthreads();
    f32x4 acck[2][2] = {}, accv[2][2] = {};
    const int n0 = wv*32;
    #pragma unroll
    for (int kt = 0; kt < 8; ++kt){
        short8 afr[2];
        #pragma unroll
        for (int mi = 0; mi < 2; ++mi){
            int row = mi*16 + (lane&15);
            int ch = kt*4 + (lane>>4);
            afr[mi] = *(const short8*)&As[row*256 + ((ch^(row&7))<<3)];
        }
        #pragma unroll
        for (int ni = 0; ni < 2; ++ni){
            int n = n0 + ni*16 + (lane&15);
            int koff = kt*32 + (lane>>4)*8;
            short8 bk = *(const short8*)&kwT[(size_t)n*DD + koff];
            short8 bv = *(const short8*)&vwT[(size_t)n*DD + koff];
            #pragma unroll
            for (int mi = 0; mi < 2; ++mi){
                acck[mi][ni] = __builtin_amdgcn_mfma_f32_16x16x32_bf16(afr[mi], bk, acck[mi][ni],0,0,0);
                accv[mi][ni] = __builtin_amdgcn_mfma_f32_16x16x32_bf16(afr[mi], bv, accv[mi][ni],0,0,0);
            }
        }
    }
    #pragma unroll
    for (int mi = 0; mi < 2; ++mi){
        #pragma unroll
        for (int ni = 0; ni < 2; ++ni){
            int n = n0 + ni*16 + (lane&15);
            float kbn = kb[n], vbn = vb[n];
            int pl0 = pblk*32 + mi*16 + (lane>>4)*4;
            us4 pk;
            #pragma unroll
            for (int r = 0; r < 4; ++r){
                kbf[((size_t)b*KVPAD + pl0 + r)*DD + n] = f2bf(acck[mi][ni][r] + kbn);
                pk[r] = f2bf(accv[mi][ni][r] + vbn);
            }
            *(us4*)&vT[((size_t)b*DD + n)*KVPAD + pl0] = pk;
        }
    }
}

// ======================= slot init: slots0 + LN_s + q =======================
__global__ __launch_bounds__(512) void k_init(const float* __restrict__ noise,
        const float* __restrict__ mu, const float* __restrict__ lsig,
        const ushort* __restrict__ qwT, const float* __restrict__ qb,
        const float* __restrict__ gs, const float* __restrict__ bs,
        float* __restrict__ slots, ushort* __restrict__ qbuf){
    __shared__ float Sld[16*256];
    __shared__ ushort Ysn[16*256];
    __shared__ float part[8][16][2];
    __shared__ float stats[16][2];
    const int t = threadIdx.x, lane = t & 63, w = t >> 6;
    const int bb = blockIdx.x, rbase = bb*16;
    {
        int row = t>>5, ch = t&31; int d = ch*8;
        f32x4 n0 = *(const f32x4*)&noise[(size_t)(rbase+row)*DD + d];
        f32x4 n1 = *(const f32x4*)&noise[(size_t)(rbase+row)*DD + d + 4];
        f32x4 m0 = *(const f32x4*)&mu[d];
        f32x4 m1 = *(const f32x4*)&mu[d+4];
        f32x4 l0 = *(const f32x4*)&lsig[d];
        f32x4 l1 = *(const f32x4*)&lsig[d+4];
        f32x4 s0, s1;
        #pragma unroll
        for (int j = 0; j < 4; ++j){
            s0[j] = m0[j] + expf(l0[j])*n0[j];
            s1[j] = m1[j] + expf(l1[j])*n1[j];
        }
        *(f32x4*)&slots[(size_t)(rbase+row)*DD + d] = s0;
        *(f32x4*)&slots[(size_t)(rbase+row)*DD + d + 4] = s1;
        *(f32x4*)&Sld[row*256 + d] = s0;
        *(f32x4*)&Sld[row*256 + d + 4] = s1;
    }
    __syncthreads();
    f32x4 sv[2];
    #pragma unroll
    for (int sub = 0; sub < 2; ++sub){
        int d0 = w*32 + sub*16 + (lane>>4)*4;
        sv[sub] = *(const f32x4*)&Sld[(lane&15)*256 + d0];
    }
    {
        float lsum = 0.f, lsq = 0.f;
        #pragma unroll
        for (int sub = 0; sub < 2; ++sub)
            #pragma unroll
            for (int r = 0; r < 4; ++r){ float v = sv[sub][r]; lsum += v; lsq += v*v; }
        lsum += __shfl_xor(lsum, 16, 64); lsum += __shfl_xor(lsum, 32, 64);
        lsq  += __shfl_xor(lsq, 16, 64);  lsq  += __shfl_xor(lsq, 32, 64);
        if (lane < 16){ part[w][lane][0] = lsum; part[w][lane][1] = lsq; }
    }
    __syncthreads();
    if (t < 16){
        float a = 0.f, c = 0.f;
        #pragma unroll
        for (int i = 0; i < 8; ++i){ a += part[i][t][0]; c += part[i][t][1]; }
        float mean = a*(1.f/256.f);
        stats[t][0] = mean;
        stats[t][1] = rsqrtf(c*(1.f/256.f) - mean*mean + 1e-5f);
    }
    __syncthreads();
    {
        int slot = lane&15;
        float mean = stats[slot][0], rs = stats[slot][1];
        #pragma unroll
        for (int sub = 0; sub < 2; ++sub){
            int d0 = w*32 + sub*16 + (lane>>4)*4;
            f32x4 g4 = *(const f32x4*)&gs[d0];
            f32x4 b4 = *(const f32x4*)&bs[d0];
            us4 o;
            #pragma unroll
            for (int r = 0; r < 4; ++r) o[r] = f2bf((sv[sub][r]-mean)*rs*g4[r] + b4[r]);
            int ch = d0>>3;
            *(us4*)&Ysn[slot*256 + ((ch^(slot&7))<<3) + (d0&7)] = o;
        }
    }
    __syncthreads();
    f32x4 qa[2] = {};
    #pragma unroll
    for (int kt = 0; kt < 8; ++kt){
        short8 ysn = ldsY(Ysn, 256, kt, lane);
        #pragma unroll
        for (int sub = 0; sub < 2; ++sub){
            int nrow = w*32 + sub*16 + (lane&15);
            short8 xx = gX(qwT, 256, nrow, kt, lane);
            qa[sub] = __builtin_amdgcn_mfma_f32_16x16x32_bf16(xx, ysn, qa[sub], 0,0,0);
        }
    }
    #pragma unroll
    for (int sub = 0; sub < 2; ++sub){
        int qd0 = w*32 + sub*16 + (lane>>4)*4;
        f32x4 qb4 = *(const f32x4*)&qb[qd0];
        us4 o;
        #pragma unroll
        for (int r = 0; r < 4; ++r) o[r] = f2bf((qa[sub][r]+qb4[r])*0.0625f);
        *(us4*)&qbuf[(size_t)(rbase+(lane&15))*DD + qd0] = o;
    }
}

// ======================= merged slot iteration: attn + GRU + FF + next-q =======================
__global__ __launch_bounds__(512) void k_slot(
        const ushort* __restrict__ qbuf, const ushort* __restrict__ kbf,
        const ushort* __restrict__ vT, float* __restrict__ slots,
        ushort* __restrict__ qout,
        const ushort* __restrict__ wihT, const ushort* __restrict__ whhT,
        const float* __restrict__ bih, const float* __restrict__ bhh,
        const ushort* __restrict__ w1T, const float* __restrict__ b1,
        const ushort* __restrict__ w2T, const float* __restrict__ b2,
        const float* __restrict__ gff, const float* __restrict__ bff,
        const float* __restrict__ gs, const float* __restrict__ bs,
        const ushort* __restrict__ qwT, const float* __restrict__ qb,
        float* __restrict__ out_slots, float* __restrict__ out_attn,
        int final_){
    __shared__ ushort Yq[16*256];
    __shared__ ushort Xat[16*256];
    __shared__ ushort Yupd[16*256];
    __shared__ ushort Yslb[16*256];
    __shared__ ushort Ysn[16*256];
    __shared__ ushort Yh[16*512];
    __shared__ float wpart[8][16];
    __shared__ float invk[16];
    __shared__ float part[8][16][2];
    __shared__ float stats[16][2];
    const int t = threadIdx.x, lane = t & 63, w = t >> 6;
    const int b = blockIdx.x;
    const int rbase = b * NSLOT;
    const int srow = lane & 15;
    const int srd = (srow < NSLOT) ? srow : 0;

    if (t < 256){
        int row = t>>5, ch = t&31;
        short8 v = *(const short8*)&qbuf[(size_t)(rbase+row)*DD + ch*8];
        *(short8*)&Yq[row*256 + ((ch^(row&7))<<3)] = v;
        f32x4 s0 = *(const f32x4*)&slots[(size_t)(rbase+row)*DD + ch*8];
        f32x4 s1 = *(const f32x4*)&slots[(size_t)(rbase+row)*DD + ch*8 + 4];
        short8 sv;
        #pragma unroll
        for (int j = 0; j < 4; ++j){ sv[j] = (short)f2bf(s0[j]); sv[4+j] = (short)f2bf(s1[j]); }
        *(short8*)&Yslb[row*256 + ((ch^(row&7))<<3)] = sv;
    } else {
        int i = t - 256;
        int row = (i>>5) + 8, ch = i&31;
        short8 z;
        #pragma unroll
        for (int j = 0; j < 8; ++j) z[j] = 0;
        *(short8*)&Yq[row*256 + ((ch^(row&7))<<3)] = z;
        *(short8*)&Yupd[row*256 + ((ch^(row&7))<<3)] = z;
        *(short8*)&Yslb[row*256 + ((ch^(row&7))<<3)] = z;
    }
    __syncthreads();
    // ===== QK^T + softmax over slots =====
    {
        short8 yf[8];
        #pragma unroll
        for (int kt = 0; kt < 8; ++kt) yf[kt] = ldsY(Yq, 256, kt, lane);
        float ps = 0.f;
        #pragma unroll
        for (int rep = 0; rep < 2; ++rep){
            int f = w + rep*8;
            if (f < 14){
                f32x4 acc = {};
                #pragma unroll
                for (int kt = 0; kt < 8; ++kt){
                    short8 xx = gX(kbf + (size_t)b*KVPAD*DD, 256, f*16 + (lane&15), kt, lane);
                    acc = __builtin_amdgcn_mfma_f32_16x16x32_bf16(xx, yf[kt], acc, 0,0,0);
                }
                int k0 = f*16 + (lane>>4)*4;
                us4 o;
                #pragma unroll
                for (int r = 0; r < 4; ++r){
                    float v = acc[r];
                    float mx = v;
                    mx = fmaxf(mx, __shfl_xor(mx, 1, 64));
                    mx = fmaxf(mx, __shfl_xor(mx, 2, 64));
                    mx = fmaxf(mx, __shfl_xor(mx, 4, 64));
                    float e = expf(v - mx);
                    float se = e;
                    se += __shfl_xor(se, 1, 64);
                    se += __shfl_xor(se, 2, 64);
                    se += __shfl_xor(se, 4, 64);
                    float val = e/se + 1e-8f;
                    if (k0 + r >= HWN) val = 0.f;
                    ps += val;
                    o[r] = f2bf(val);
                }
                int ch = k0 >> 3;
                *(us4*)&Xat[srow*256 + ((ch^(srow&7))<<3) + (k0&7)] = o;
            }
        }
        ps += __shfl_xor(ps, 16, 64);
        ps += __shfl_xor(ps, 32, 64);
        if (lane < 16) wpart[w][lane] = ps;
    }
    __syncthreads();
    if (t < 16){
        float s = 0.f;
        #pragma unroll
        for (int i = 0; i < 8; ++i) s += wpart[i][t];
        invk[t] = 1.f/s;
    }
    __syncthreads();
    // ===== PV -> Yupd (in LDS) =====
    {
        short8 xa[7];
        #pragma unroll
        for (int kt = 0; kt < 7; ++kt) xa[kt] = ldsY(Xat, 256, kt, lane);
        f32x4 iv = *(const f32x4*)&invk[(lane>>4)*4];
        #pragma unroll
        for (int i = 0; i < 2; ++i){
            int d0 = (w*2 + i)*16;
            f32x4 acc = {};
            #pragma unroll
            for (int kt = 0; kt < 7; ++kt){
                short8 y = gX(vT + (size_t)b*DD*KVPAD, KVPAD, d0 + (lane&15), kt, lane);
                acc = __builtin_amdgcn_mfma_f32_16x16x32_bf16(xa[kt], y, acc, 0,0,0);
            }
            #pragma unroll
            for (int r = 0; r < 4; ++r){
                int s2 = (lane>>4)*4 + r;
                if (s2 < NSLOT){
                    int d = d0 + (lane&15);
                    int ch = d >> 3;
                    Yupd[s2*256 + ((ch^(s2&7))<<3) + (d&7)] = f2bf(acc[r]*iv[r]);
                }
            }
        }
    }
    if (final_){
        for (int idx = t; idx < NSLOT*HWN; idx += 512){
            int slot = idx/HWN, key = idx - slot*HWN;
            int ch = key >> 3;
            out_attn[(size_t)b*NSLOT*HWN + idx] =
                bf2f(Xat[slot*256 + ((ch^(slot&7))<<3) + (key&7)]) * invk[slot];
        }
    }
    __syncthreads();
    // ===== gi/gh GEMMs =====
    f32x4 gi[6] = {}, gh[6] = {};
    #pragma unroll
    for (int kt = 0; kt < 8; ++kt){
        short8 yu = ldsY(Yupd, 256, kt, lane);
        short8 ys = ldsY(Yslb, 256, kt, lane);
        #pragma unroll
        for (int g = 0; g < 3; ++g)
            #pragma unroll
            for (int sub = 0; sub < 2; ++sub){
                int nrow = g*256 + w*32 + sub*16 + (lane&15);
                short8 xi = gX(wihT, 256, nrow, kt, lane);
                short8 xh = gX(whhT, 256, nrow, kt, lane);
                gi[g*2+sub] = __builtin_amdgcn_mfma_f32_16x16x32_bf16(xi, yu, gi[g*2+sub], 0,0,0);
                gh[g*2+sub] = __builtin_amdgcn_mfma_f32_16x16x32_bf16(xh, ys, gh[g*2+sub], 0,0,0);
            }
    }
    // ===== GRU combine (lane-local triplets) =====
    f32x4 snew[2];
    #pragma unroll
    for (int sub = 0; sub < 2; ++sub){
        int d0 = w*32 + sub*16 + (lane>>4)*4;
        f32x4 sp  = *(const f32x4*)&slots[(size_t)(rbase + srd)*DD + d0];
        f32x4 bir = *(const f32x4*)&bih[d0];
        f32x4 biz = *(const f32x4*)&bih[256 + d0];
        f32x4 bin = *(const f32x4*)&bih[512 + d0];
        f32x4 bhr = *(const f32x4*)&bhh[d0];
        f32x4 bhz = *(const f32x4*)&bhh[256 + d0];
        f32x4 bhn = *(const f32x4*)&bhh[512 + d0];
        #pragma unroll
        for (int r = 0; r < 4; ++r){
            float ir = gi[0+sub][r] + bir[r];
            float iz = gi[2+sub][r] + biz[r];
            float in_ = gi[4+sub][r] + bin[r];
            float hr = gh[0+sub][r] + bhr[r];
            float hz = gh[2+sub][r] + bhz[r];
            float hn = gh[4+sub][r] + bhn[r];
            float rr = sigm(ir + hr);
            float zz = sigm(iz + hz);
            float nn = tanhf(in_ + rr*hn);
            snew[sub][r] = (1.f - zz)*nn + zz*sp[r];
        }
    }
    // ===== LN_ff =====
    {
        float lsum = 0.f, lsq = 0.f;
        #pragma unroll
        for (int sub = 0; sub < 2; ++sub)
            #pragma unroll
            for (int r = 0; r < 4; ++r){ float v = snew[sub][r]; lsum += v; lsq += v*v; }
        lsum += __shfl_xor(lsum, 16, 64); lsum += __shfl_xor(lsum, 32, 64);
        lsq  += __shfl_xor(lsq, 16, 64);  lsq  += __shfl_xor(lsq, 32, 64);
        if (lane < 16){ part[w][lane][0] = lsum; part[w][lane][1] = lsq; }
    }
    __syncthreads();
    if (t < 16){
        float a = 0.f, c = 0.f;
        #pragma unroll
        for (int i = 0; i < 8; ++i){ a += part[i][t][0]; c += part[i][t][1]; }
        float mean = a*(1.f/256.f);
        stats[t][0] = mean;
        stats[t][1] = rsqrtf(c*(1.f/256.f) - mean*mean + 1e-5f);
    }
    __syncthreads();
    {
        float mean = stats[srow][0], rs = stats[srow][1];
        #pragma unroll
        for (int sub = 0; sub < 2; ++sub){
            int d0 = w*32 + sub*16 + (lane>>4)*4;
            f32x4 g4 = *(const f32x4*)&gff[d0];
            f32x4 b4 = *(const f32x4*)&bff[d0];
            us4 o;
            #pragma unroll
            for (int r = 0; r < 4; ++r) o[r] = f2bf((snew[sub][r]-mean)*rs*g4[r] + b4[r]);
            int ch = d0 >> 3;
            *(us4*)&Ysn[srow*256 + ((ch^(srow&7))<<3) + (d0&7)] = o;
        }
    }
    __syncthreads();
    // ===== ff1 =====
    {
        f32x4 hh[4] = {};
        #pragma unroll
        for (int kt = 0; kt < 8; ++kt){
            short8 ysn = ldsY(Ysn, 256, kt, lane);
            #pragma unroll
            for (int s2 = 0; s2 < 4; ++s2){
                int nrow = w*64 + s2*16 + (lane&15);
                short8 xx = gX(w1T, 256, nrow, kt, lane);
                hh[s2] = __builtin_amdgcn_mfma_f32_16x16x32_bf16(xx, ysn, hh[s2], 0,0,0);
            }
        }
        #pragma unroll
        for (int s2 = 0; s2 < 4; ++s2){
            int n0 = w*64 + s2*16 + (lane>>4)*4;
            f32x4 b14 = *(const f32x4*)&b1[n0];
            us4 o;
            #pragma unroll
            for (int r = 0; r < 4; ++r) o[r] = f2bf(fmaxf(hh[s2][r] + b14[r], 0.f));
            int ch = n0 >> 3;
            *(us4*)&Yh[srow*512 + ((ch^(srow&7))<<3) + (n0&7)] = o;
        }
    }
    __syncthreads();
    // ===== ff2 + residual =====
    f32x4 ns[2];
    {
        f32x4 o2[2] = {};
        #pragma unroll
        for (int kt = 0; kt < 16; ++kt){
            short8 yh = ldsY(Yh, 512, kt, lane);
            #pragma unroll
            for (int sub = 0; sub < 2; ++sub){
                int nrow = w*32 + sub*16 + (lane&15);
                short8 xx = gX(w2T, 512, nrow, kt, lane);
                o2[sub] = __builtin_amdgcn_mfma_f32_16x16x32_bf16(xx, yh, o2[sub], 0,0,0);
            }
        }
        float* dst = final_ ? out_slots : slots;
        #pragma unroll
        for (int sub = 0; sub < 2; ++sub){
            int d0 = w*32 + sub*16 + (lane>>4)*4;
            f32x4 b24 = *(const f32x4*)&b2[d0];
            #pragma unroll
            for (int r = 0; r < 4; ++r) ns[sub][r] = o2[sub][r] + b24[r] + snew[sub][r];
            if (srow < NSLOT)
                *(f32x4*)&dst[(size_t)(rbase + srow)*DD + d0] = ns[sub];
        }
    }
    if (final_) return;
    // ===== LN_s + next q =====
    {
        float lsum = 0.f, lsq = 0.f;
        #pragma unroll
        for (int sub = 0; sub < 2; ++sub)
            #pragma unroll
            for (int r = 0; r < 4; ++r){ float v = ns[sub][r]; lsum += v; lsq += v*v; }
        lsum += __shfl_xor(lsum, 16, 64); lsum += __shfl_xor(lsum, 32, 64);
        lsq  += __shfl_xor(lsq, 16, 64);  lsq  += __shfl_xor(lsq, 32, 64);
        if (lane < 16){ part[w][lane][0] = lsum; part[w][lane][1] = lsq; }
    }
    __syncthreads();
    if (t < 16){
        float a = 0.f, c = 0.f;
        #pragma unroll
        for (int i = 0; i < 8; ++i){ a += part[i][t][0]; c += part[i][t][1]; }
        float mean = a*(1.f/256.f);
        stats[t][0] = mean;
        stats[t][1] = rsqrtf(c*(1.f/256.f) - mean*mean + 1e-5f);
    }
    __syncthreads();
    {
        float mean = stats[srow][0], rs = stats[srow][1];
        #pragma unroll
        for (int sub = 0; sub < 2; ++sub){
            int d0 = w*32 + sub*16 + (lane>>4)*4;
            f32x4 g4 = *(const f32x4*)&gs[d0];
            f32x4 b4 = *(const f32x4*)&bs[d0];
            us4 o;
            #pragma unroll
            for (int r = 0; r < 4; ++r) o[r] = f2bf((ns[sub][r]-mean)*rs*g4[r] + b4[r]);
            int ch = d0 >> 3;
            *(us4*)&Ysn[srow*256 + ((ch^(srow&7))<<3) + (d0&7)] = o;
        }
    }
    __syncthreads();
    {
        f32x4 qa[2] = {};
        #pragma unroll
        for (int kt = 0; kt < 8; ++kt){
            short8 ysn = ldsY(Ysn, 256, kt, lane);
            #pragma unroll
            for (int sub = 0; sub < 2; ++sub){
                int nrow = w*32 + sub*16 + (lane&15);
                short8 xx = gX(qwT, 256, nrow, kt, lane);
                qa[sub] = __builtin_amdgcn_mfma_f32_16x16x32_bf16(xx, ysn, qa[sub], 0,0,0);
            }
        }
        #pragma unroll
        for (int sub = 0; sub < 2; ++sub){
            int qd0 = w*32 + sub*16 + (lane>>4)*4;
            f32x4 qb4 = *(const f32x4*)&qb[qd0];
            us4 o;
            #pragma unroll
            for (int r = 0; r < 4; ++r) o[r] = f2bf((qa[sub][r]+qb4[r])*0.0625f);
            if (srow < NSLOT)
                *(us4*)&qout[(size_t)(rbase + srow)*DD + qd0] = o;
        }
    }
}

extern "C" void kernel_launch(void* const* d_in, const int* in_sizes, int n_in,
                              void* d_out, int out_size, void* d_ws, size_t ws_size,
                              hipStream_t stream) {
    const float* x      = (const float*)d_in[0];
    const float* noise  = (const float*)d_in[1];
    const float* conv_w = (const float*)d_in[2];
    const float* conv_b = (const float*)d_in[3];
    const float* pos    = (const float*)d_in[4];
    const float* mu     = (const float*)d_in[5];
    const float* logsig = (const float*)d_in[6];
    const float* qw  = (const float*)d_in[7];
    const float* qb  = (const float*)d_in[8];
    const float* kw  = (const float*)d_in[9];
    const float* kb  = (const float*)d_in[10];
    const float* vw  = (const float*)d_in[11];
    const float* vb  = (const float*)d_in[12];
    const float* wih = (const float*)d_in[13];
    const float* whh = (const float*)d_in[14];
    const float* bih = (const float*)d_in[15];
    const float* bhh = (const float*)d_in[16];
    const float* w1  = (const float*)d_in[17];
    const float* b1  = (const float*)d_in[18];
    const float* w2  = (const float*)d_in[19];
    const float* b2  = (const float*)d_in[20];
    const float* g_in = (const float*)d_in[21];
    const float* b_in = (const float*)d_in[22];
    const float* g_s  = (const float*)d_in[23];
    const float* b_s  = (const float*)d_in[24];
    const float* g_ff = (const float*)d_in[25];
    const float* b_ff = (const float*)d_in[26];

    char* w = (char*)d_ws;
    ushort* xt     = (ushort*)w; w += (size_t)MTOT*DD*2;
    ushort* kbf    = (ushort*)w; w += (size_t)BB*KVPAD*DD*2;
    ushort* vT     = (ushort*)w; w += (size_t)BB*DD*KVPAD*2;
    ushort* cwT    = (ushort*)w; w += (size_t)DD*CIN*2;
    ushort* qwT    = (ushort*)w; w += (size_t)DD*DD*2;
    ushort* kwT    = (ushort*)w; w += (size_t)DD*DD*2;
    ushort* vwT    = (ushort*)w; w += (size_t)DD*DD*2;
    ushort* wihT   = (ushort*)w; w += (size_t)768*DD*2;
    ushort* whhT   = (ushort*)w; w += (size_t)768*DD*2;
    ushort* w1T    = (ushort*)w; w += (size_t)512*DD*2;
    ushort* w2T    = (ushort*)w; w += (size_t)DD*512*2;
    ushort* qbb    = (ushort*)w; w += (size_t)BB*NSLOT*DD*2;
    float*  slotsb = (float*)w;  w += (size_t)BB*NSLOT*DD*4;

    float* out_slots = (float*)d_out;
    float* out_attn  = (float*)d_out + (size_t)BB*NSLOT*DD;

    TD8 td;
    td.a[0] = { conv_w, cwT, 2048, 256,    0 };
    td.a[1] = { qw,     qwT,  256, 256,  512 };
    td.a[2] = { kw,     kwT,  256, 256,  576 };
    td.a[3] = { vw,     vwT,  256, 256,  640 };
    td.a[4] = { wih,    wihT, 256, 768,  704 };
    td.a[5] = { whh,    whhT, 256, 768,  896 };
    td.a[6] = { w1,     w1T,  256, 512, 1088 };
    td.a[7] = { w2,     w2T,  512, 256, 1216 };

    k_prep<<<1344, 256, 0, stream>>>(td);
    k_proj<<<dim3(2, 196), 512, 0, stream>>>(x, cwT, conv_b, pos, xt);
    k_kv<<<448, 512, 0, stream>>>(xt, kwT, vwT, kb, vb, g_in, b_in, kbf, vT);
    k_init<<<32, 512, 0, stream>>>(noise, mu, logsig, qwT, qb, g_s, b_s, slotsb, qbb);
    for (int it = 0; it < 3; ++it){
        k_slot<<<BB, 512, 0, stream>>>(qbb, kbf, vT, slotsb, qbb,
                                       wihT, whhT, bih, bhh, w1T, b1, w2T, b2,
                                       g_ff, b_ff, g_s, b_s, qwT, qb,
                                       out_slots, out_attn, it == 2);
    }
}